// Round 7
// baseline (231.925 us; speedup 1.0000x reference)
//
#include <hip/hip_runtime.h>
#include <stdint.h>

using bf16x8 = __attribute__((ext_vector_type(8))) __bf16;
using f32x4  = __attribute__((ext_vector_type(4))) float;
using f32x16 = __attribute__((ext_vector_type(16))) float;
using u16x8  = __attribute__((ext_vector_type(8))) uint16_t;

#define S_LEN 4096
#define E_DIM 2048
#define D_DIM 128
#define H_NUM 16
#define G_NUM 4
#define QKV_N 3072
#define SCALE 0.08838834764831845f

__device__ inline float bf2f(uint16_t b) {
  union { uint32_t u; float f; } v; v.u = ((uint32_t)b) << 16; return v.f;
}
__device__ inline uint16_t f2bf(float f) {
  union { float f; uint32_t u; } v; v.f = f;
  uint32_t u = v.u + 0x7FFFu + ((v.u >> 16) & 1u);
  return (uint16_t)(u >> 16);
}
__device__ inline uint32_t packbf(float a, float b) {  // (lo=a, hi=b) round-half-up
  union { float f; uint32_t u; } x, y; x.f = a; y.f = b;
  return ((x.u + 0x8000u) >> 16) | ((y.u + 0x8000u) & 0xFFFF0000u);
}
__device__ inline void plswap(uint32_t& a, uint32_t& b) {
  asm volatile("v_permlane32_swap_b32 %0, %1" : "+v"(a), "+v"(b));
}
__device__ inline void gload_lds16(const void* g, void* l) {
  __builtin_amdgcn_global_load_lds((const __attribute__((address_space(1))) void*)g,
                                   (__attribute__((address_space(3))) void*)l, 16, 0, 0);
}

// ---------------- fp32 -> bf16 convert (8 elems/thread) ----------------
__global__ __launch_bounds__(256) void conv_f2b(const float* __restrict__ in,
                                                uint16_t* __restrict__ out) {
  const size_t i = ((size_t)blockIdx.x * 256 + threadIdx.x) * 8;
  float4 a = *(const float4*)(in + i);
  float4 b = *(const float4*)(in + i + 4);
  u16x8 o;
  o[0] = f2bf(a.x); o[1] = f2bf(a.y); o[2] = f2bf(a.z); o[3] = f2bf(a.w);
  o[4] = f2bf(b.x); o[5] = f2bf(b.y); o[6] = f2bf(b.z); o[7] = f2bf(b.w);
  *(u16x8*)(out + i) = o;
}

// ---------------- transpose fp32 -> bf16: out[c][r] = bf16(in[r][c]) ----------------
__global__ __launch_bounds__(256) void transpose_f2b(
    const float* __restrict__ in, uint16_t* __restrict__ out,
    int ldi, int ldo)
{
  __shared__ __align__(16) uint16_t tile[64][65];
  const int c0 = blockIdx.x * 64, r0 = blockIdx.y * 64;
  const int t = threadIdx.x;
#pragma unroll
  for (int i = 0; i < 16; ++i) {
    int idx = t + i * 256;
    int r = idx >> 6, c = idx & 63;
    tile[r][c] = f2bf(in[(size_t)(r0 + r) * ldi + c0 + c]);
  }
  __syncthreads();
#pragma unroll
  for (int i = 0; i < 16; ++i) {
    int idx = t + i * 256;
    int cc = idx >> 6, rr = idx & 63;
    out[(size_t)(c0 + cc) * ldo + r0 + rr] = tile[rr][cc];
  }
}

// ---------------- transpose bf16 -> bf16 (for V) ----------------
__global__ __launch_bounds__(256) void transpose_bf16(
    const uint16_t* __restrict__ in, uint16_t* __restrict__ out,
    int ldi, int ldo)
{
  __shared__ __align__(16) uint16_t tile[64][65];
  const int c0 = blockIdx.x * 64, r0 = blockIdx.y * 64;
  const int t = threadIdx.x;
#pragma unroll
  for (int i = 0; i < 16; ++i) {
    int idx = t + i * 256;
    int r = idx >> 6, c = idx & 63;
    tile[r][c] = in[(size_t)(r0 + r) * ldi + c0 + c];
  }
  __syncthreads();
#pragma unroll
  for (int i = 0; i < 16; ++i) {
    int idx = t + i * 256;
    int cc = idx >> 6, rr = idx & 63;
    out[(size_t)(c0 + cc) * ldo + r0 + rr] = tile[rr][cc];
  }
}

// ---------------- deep-pipelined GEMM: C = A[M][K] * Bt[N][K]^T ----------------
// 256(M) x BN tile, BK=32, 4-deep LDS ring, counted vmcnt (never 0 in loop),
// raw s_barrier (1/tile), T2 swizzle (slot = lq ^ ((row+(row>>2))&3)), T5 setprio.
// 8 waves (2M x 4N): wave output 128 x (BN/4). LPS = per-thread loads/stage.
template<int BN, bool F32OUT>
__global__ __launch_bounds__(512, 2) void gemm_pipe(
    const uint16_t* __restrict__ A, const uint16_t* __restrict__ Bt,
    uint16_t* __restrict__ Cb, float* __restrict__ Cf, int M, int N, int K, int nwgm)
{
  constexpr int WN = BN / 4;        // wave N width
  constexpr int NF = WN / 16;       // N fragments per wave
  __shared__ __align__(16) uint16_t sA[4 * 256 * 32];
  __shared__ __align__(16) uint16_t sB[4 * BN * 32];

  const int nwg = gridDim.x;
  const int id = ((int)blockIdx.x & 7) * (nwg >> 3) + ((int)blockIdx.x >> 3);  // XCD swizzle
  const int m0 = (id % nwgm) * 256, n0 = (id / nwgm) * BN;
  const int tid = threadIdx.x, w = tid >> 6, lane = tid & 63;
  const int lr = lane & 15, lq = lane >> 4;
  const int wr = w >> 2, wc = w & 3;

  f32x4 acc[8][NF];
#pragma unroll
  for (int i = 0; i < 8; ++i)
#pragma unroll
    for (int j = 0; j < NF; ++j) acc[i][j] = (f32x4){0.f, 0.f, 0.f, 0.f};

  // staging geometry: thread t covers row (i*128 + t>>2), 16B slot (t&3).
  // LDS dest is linear (tid*16 per 128-row half); global source pre-swizzled.
  const int srow = tid >> 2;
  const int fsw = (srow + (srow >> 2)) & 3;              // f(row), same for both halves
  const int chnk = (tid & 3) ^ fsw;                      // global 16B chunk
  const char* gA0 = (const char*)A + (size_t)(m0 + srow) * K * 2 + chnk * 16;
  const char* gA1 = (const char*)A + (size_t)(m0 + 128 + srow) * K * 2 + chnk * 16;
  const char* gB0 = (const char*)Bt + (size_t)(n0 + srow) * K * 2 + chnk * 16;
  const char* gB1 = (const char*)Bt + (size_t)(n0 + 128 + srow) * K * 2 + chnk * 16;
  char* const lA = (char*)sA + tid * 16;
  char* const lB = (char*)sB + tid * 16;

#define G_STAGE(kt)                                                      \
  {                                                                      \
    const int _b = (kt) & 3;                                             \
    const size_t _ko = (size_t)(kt) * 64;                                \
    gload_lds16(gA0 + _ko, lA + _b * 16384);                             \
    gload_lds16(gA1 + _ko, lA + _b * 16384 + 8192);                      \
    gload_lds16(gB0 + _ko, lB + _b * (BN * 64));                         \
    if constexpr (BN == 256) gload_lds16(gB1 + _ko, lB + _b * 16384 + 8192); \
  }

#define G_COMPUTE(t)                                                     \
  {                                                                      \
    const uint16_t* Ab = sA + ((t) & 3) * 8192;                          \
    const uint16_t* Bb = sB + ((t) & 3) * (BN * 32);                     \
    bf16x8 af[8];                                                        \
    _Pragma("unroll") for (int mf = 0; mf < 8; ++mf) {                   \
      const int rl = wr * 128 + mf * 16 + lr;                            \
      af[mf] = *(const bf16x8*)(Ab + rl * 32 + ((lq ^ ((rl + (rl >> 2)) & 3)) << 3)); \
    }                                                                    \
    bf16x8 bb[NF];                                                       \
    _Pragma("unroll") for (int nf = 0; nf < NF; ++nf) {                  \
      const int rl = wc * WN + nf * 16 + lr;                             \
      bb[nf] = *(const bf16x8*)(Bb + rl * 32 + ((lq ^ ((rl + (rl >> 2)) & 3)) << 3)); \
    }                                                                    \
    __builtin_amdgcn_s_setprio(1);                                       \
    _Pragma("unroll") for (int mf = 0; mf < 8; ++mf)                     \
      _Pragma("unroll") for (int nf = 0; nf < NF; ++nf)                  \
        acc[mf][nf] = __builtin_amdgcn_mfma_f32_16x16x32_bf16(af[mf], bb[nf], acc[mf][nf], 0, 0, 0); \
    __builtin_amdgcn_s_setprio(0);                                       \
  }

#define G_WAITN                                                           \
  if constexpr (BN == 256) { asm volatile("s_waitcnt vmcnt(8)" ::: "memory"); } \
  else { asm volatile("s_waitcnt vmcnt(6)" ::: "memory"); }
#define G_WAIT1                                                           \
  if constexpr (BN == 256) { asm volatile("s_waitcnt vmcnt(4)" ::: "memory"); } \
  else { asm volatile("s_waitcnt vmcnt(3)" ::: "memory"); }
#define G_BAR  __builtin_amdgcn_s_barrier(); asm volatile("" ::: "memory");

  const int nk = K >> 5;  // BK=32
  G_STAGE(0) G_STAGE(1) G_STAGE(2)
  G_WAITN G_BAR
  for (int t = 0; t < nk - 3; ++t) {
    G_STAGE(t + 3)
    G_COMPUTE(t)
    G_WAITN G_BAR
  }
  G_COMPUTE(nk - 3)
  G_WAIT1 G_BAR
  G_COMPUTE(nk - 2)
  asm volatile("s_waitcnt vmcnt(0)" ::: "memory");
  G_BAR
  G_COMPUTE(nk - 1)

  // epilogue: C[row = m0 + wr*128 + mf*16 + lq*4 + r][col = n0 + wc*WN + nf*16 + lr]
#pragma unroll
  for (int mf = 0; mf < 8; ++mf)
#pragma unroll
    for (int nf = 0; nf < NF; ++nf)
#pragma unroll
      for (int r = 0; r < 4; ++r) {
        const size_t row = m0 + wr * 128 + mf * 16 + lq * 4 + r;
        const int col = n0 + wc * WN + nf * 16 + lr;
        if constexpr (F32OUT) Cf[row * N + col] = acc[mf][nf][r];
        else Cb[row * N + col] = f2bf(acc[mf][nf][r]);
      }
#undef G_STAGE
#undef G_COMPUTE
#undef G_WAITN
#undef G_WAIT1
#undef G_BAR
}

// ---------------- RoPE + rearrange for q,k (cos/sin are fp32) ----------------
__global__ __launch_bounds__(256) void rope_qk(
    const uint16_t* __restrict__ qkv, const float* __restrict__ cosb,
    const float* __restrict__ sinb, uint16_t* __restrict__ q_r, uint16_t* __restrict__ k_r)
{
  const int idx = blockIdx.x * 256 + threadIdx.x;  // < 4096*1280
  const int s = idx / 1280;
  const int pp = idx - s * 1280;
  const int c0 = pp << 1;
  const uint32_t xp = *(const uint32_t*)(qkv + (size_t)s * QKV_N + c0);
  const float xe = bf2f((uint16_t)xp), xo = bf2f((uint16_t)(xp >> 16));
  const int dloc = c0 & 127;
  const int dd = dloc >> 1;
  const float cf = cosb[s * 64 + dd];
  const float sf = sinb[s * 64 + dd];
  float oe = xe * cf - xo * sf;
  float oo = xe * sf + xo * cf;
  uint16_t* dst;
  if (c0 < E_DIM) {
    oe *= SCALE; oo *= SCALE;                 // fold 1/sqrt(D) into q
    const int h = c0 >> 7;
    dst = q_r + ((size_t)h * S_LEN + s) * D_DIM + dloc;
  } else {
    const int g = (c0 - E_DIM) >> 7;
    dst = k_r + ((size_t)g * S_LEN + s) * D_DIM + dloc;
  }
  *(uint32_t*)dst = (uint32_t)f2bf(oe) | ((uint32_t)f2bf(oo) << 16);
}

// ---------------- flash attention, window [p-1024, p] ----------------
// 32x32x16 MFMA path: 4 waves x 32 q-rows (QBLK=128). Swapped QK^T puts the
// softmax row on lane&31 (1-hop reduce); P->PV A-frags built in-register via
// cvt-pack + v_permlane32_swap_b32 (zero LDS). 2x FLOP per LDS byte vs 16x16.
__global__ __launch_bounds__(256, 2) void attn_kernel(
    const uint16_t* __restrict__ q_r, const uint16_t* __restrict__ k_r,
    const uint16_t* __restrict__ v_t, uint16_t* __restrict__ o_r)
{
  __shared__ __align__(16) uint16_t sK[2][64 * 128];   // [key][d], swizzled
  __shared__ __align__(16) uint16_t sVT[2][128 * 64];  // [d][key], swizzled
  const int h = blockIdx.y, g = h >> 2;
  const int q0 = blockIdx.x * 128;
  const int tid = threadIdx.x, w = tid >> 6, lane = tid & 63;
  const int lc = lane & 31, hi = lane >> 5;
  const int pmin = q0 + w * 32, pmax = pmin + 31;
  const int pq = pmin + lc;       // this lane's softmax row (q index)

  bf16x8 aq[8];
  {
    const uint16_t* qb = q_r + ((size_t)h * S_LEN + pq) * D_DIM + hi * 8;
#pragma unroll
    for (int ks = 0; ks < 8; ++ks) aq[ks] = *(const bf16x8*)(qb + ks * 16);
  }
  f32x16 accO[4];
#pragma unroll
  for (int dt = 0; dt < 4; ++dt) accO[dt] = 0;
  float M = -1e30f, L = 0.f;

  const int jstart = (q0 >= 1024) ? (q0 - 1024) : 0;
  const int nt = (q0 + 128 - jstart) >> 6;
  const char* kb = (const char*)(k_r + ((size_t)g * S_LEN + jstart) * D_DIM);
  const char* vb = (const char*)(v_t + (size_t)g * D_DIM * S_LEN + jstart);

  const int kc_row = lane >> 4;                         // row within 4-row K chunk
  const int k_col0 = (lane & 15) << 4;                  // linear byte col (K)
  const int v_scol = (((lane & 7) ^ (lane >> 3)) << 4); // swizzled byte col (V)
  const int v_row = lane >> 3;                          // row within 8-row V chunk

#define STAGE_KV(buf, tt)                                                              \
  {                                                                                    \
    const char* kt_ = kb + (size_t)(tt) * 16384;                                       \
    const char* vt_ = vb + (size_t)(tt) * 128;                                         \
    _Pragma("unroll")                                                                  \
    for (int it = 0; it < 4; ++it) {                                                   \
      const int c = w * 4 + it;                                                        \
      const int krow = c * 4 + kc_row;                                                 \
      const int kscol = k_col0 ^ ((krow & 7) << 4);                                    \
      gload_lds16(kt_ + krow * 256 + kscol, (char*)sK[buf] + c * 1024 + lane * 16);    \
      const int vrow = c * 8 + v_row;                                                  \
      gload_lds16(vt_ + (size_t)vrow * (S_LEN * 2) + v_scol,                           \
                  (char*)sVT[buf] + c * 1024 + lane * 16);                             \
    }                                                                                  \
  }

  STAGE_KV(0, 0)
  asm volatile("s_waitcnt vmcnt(0)" ::: "memory");
  __syncthreads();

  for (int t = 0; t < nt; ++t) {
    const int b = t & 1;
    if (t + 1 < nt) STAGE_KV(b ^ 1, t + 1)
    const int j0 = jstart + t * 64;
    const uint16_t* Kb = sK[b];
    const uint16_t* Vb = sVT[b];

    const bool active = (j0 <= pmax) && (j0 + 63 + 1024 >= pmin);
    if (active) {
      f32x16 accS[2];
      accS[0] = 0; accS[1] = 0;
      __builtin_amdgcn_s_setprio(1);
#pragma unroll
      for (int rt = 0; rt < 2; ++rt) {
        const int krow = rt * 32 + lc;
        const int ksw = (krow & 7) << 3;
#pragma unroll
        for (int ks = 0; ks < 8; ++ks) {
          bf16x8 ak = *(const bf16x8*)(Kb + krow * 128 + ((ks * 16 + hi * 8) ^ ksw));
          accS[rt] = __builtin_amdgcn_mfma_f32_32x32x16_bf16(ak, aq[ks], accS[rt], 0, 0, 0);
        }
      }
      __builtin_amdgcn_s_setprio(0);

      const bool need_mask = (j0 + 63 > pmin) || (j0 < pmax - 1024);
      if (need_mask) {
#pragma unroll
        for (int rt = 0; rt < 2; ++rt)
#pragma unroll
          for (int c = 0; c < 16; ++c) {
            const int j = j0 + rt * 32 + (c & 3) + 8 * (c >> 2) + 4 * hi;
            const bool ok = (j <= pq) && (j + 1024 >= pq);
            accS[rt][c] = ok ? accS[rt][c] : -1e30f;
          }
      }

      float mx = accS[0][0];
#pragma unroll
      for (int rt = 0; rt < 2; ++rt)
#pragma unroll
        for (int c = 0; c < 16; ++c) mx = fmaxf(mx, accS[rt][c]);
      mx = fmaxf(mx, __shfl_xor(mx, 32));

      if (__any(mx > M + 4.f)) {
        const float Mn = fmaxf(M, mx);
        const float al = __expf(M - Mn);
        M = Mn;
        L *= al;
        float alr[16];
#pragma unroll
        for (int c = 0; c < 16; ++c) alr[c] = __shfl(al, (c & 3) + 8 * (c >> 2) + 4 * hi);
#pragma unroll
        for (int dt = 0; dt < 4; ++dt)
#pragma unroll
          for (int c = 0; c < 16; ++c) accO[dt][c] *= alr[c];
      }

      float rs = 0.f;
#pragma unroll
      for (int rt = 0; rt < 2; ++rt)
#pragma unroll
        for (int c = 0; c < 16; ++c) {
          const float pv = __expf(accS[rt][c] - M);
          accS[rt][c] = pv;
          rs += pv;
        }
      rs += __shfl_xor(rs, 32);
      L += rs;

      __builtin_amdgcn_s_setprio(1);
#pragma unroll
      for (int rt = 0; rt < 2; ++rt) {
        uint32_t wv[8];
#pragma unroll
        for (int jj = 0; jj < 8; ++jj)
          wv[jj] = packbf(accS[rt][2 * jj], accS[rt][2 * jj + 1]);
        plswap(wv[0], wv[2]); plswap(wv[1], wv[3]);
        plswap(wv[4], wv[6]); plswap(wv[5], wv[7]);
#pragma unroll
        for (int sub = 0; sub < 2; ++sub) {
          union { uint32_t u[4]; bf16x8 v; } ap;
          ap.u[0] = wv[sub * 4 + 0]; ap.u[1] = wv[sub * 4 + 1];
          ap.u[2] = wv[sub * 4 + 2]; ap.u[3] = wv[sub * 4 + 3];
          const int kbase = rt * 32 + sub * 16 + hi * 8;
#pragma unroll
          for (int dt = 0; dt < 4; ++dt) {
            const int vrow = dt * 32 + lc;
            bf16x8 bv = *(const bf16x8*)(Vb + vrow * 64 + (kbase ^ ((vrow & 7) << 3)));
            accO[dt] = __builtin_amdgcn_mfma_f32_32x32x16_bf16(ap.v, bv, accO[dt], 0, 0, 0);
          }
        }
      }
      __builtin_amdgcn_s_setprio(0);
    }

    asm volatile("s_waitcnt vmcnt(0)" ::: "memory");
    __syncthreads();
  }

  const float ivl = 1.f / L;
  float il[16];
#pragma unroll
  for (int c = 0; c < 16; ++c) il[c] = __shfl(ivl, (c & 3) + 8 * (c >> 2) + 4 * hi);
#pragma unroll
  for (int dt = 0; dt < 4; ++dt)
#pragma unroll
    for (int c = 0; c < 16; ++c) {
      const int p = pmin + (c & 3) + 8 * (c >> 2) + 4 * hi;
      o_r[(size_t)p * E_DIM + h * D_DIM + dt * 32 + lc] = f2bf(accO[dt][c] * il[c]);
    }
}

extern "C" void kernel_launch(void* const* d_in, const int* in_sizes, int n_in,
                              void* d_out, int out_size, void* d_ws, size_t ws_size,
                              hipStream_t stream) {
  const float* x     = (const float*)d_in[0];
  const float* fcos  = (const float*)d_in[1];
  const float* fsin  = (const float*)d_in[2];
  const float* w_in  = (const float*)d_in[3];
  const float* w_out = (const float*)d_in[4];
  float* out = (float*)d_out;

  char* ws = (char*)d_ws;
  size_t off = 0;
  uint16_t* w_inT  = (uint16_t*)(ws + off); off += (size_t)QKV_N * E_DIM * 2;      // 3072x2048 bf16
  uint16_t* w_outT = (uint16_t*)(ws + off); off += (size_t)E_DIM * E_DIM * 2;      // 2048x2048 bf16
  uint16_t* qkv    = (uint16_t*)(ws + off); off += (size_t)S_LEN * QKV_N * 2;      // 4096x3072 bf16
  uint16_t* q_r    = (uint16_t*)(ws + off); off += (size_t)H_NUM * S_LEN * D_DIM * 2;
  uint16_t* k_r    = (uint16_t*)(ws + off); off += (size_t)G_NUM * S_LEN * D_DIM * 2;
  uint16_t* v_t    = (uint16_t*)(ws + off); off += (size_t)G_NUM * D_DIM * S_LEN * 2;
  uint16_t* o_r    = (uint16_t*)(ws + off); off += (size_t)S_LEN * E_DIM * 2;
  // x_bf aliases o_r: x_bf is consumed by gemm1 before attn writes o_r (stream-ordered).
  uint16_t* x_bf   = o_r;  // 4096x2048 bf16, same size as o_r

  // edge conversions: fp32 -> bf16
  conv_f2b<<<(S_LEN * E_DIM) / (256 * 8), 256, 0, stream>>>(x, x_bf);
  transpose_f2b<<<dim3(QKV_N / 64, E_DIM / 64), 256, 0, stream>>>(w_in, w_inT, QKV_N, E_DIM);
  transpose_f2b<<<dim3(E_DIM / 64, E_DIM / 64), 256, 0, stream>>>(w_out, w_outT, E_DIM, E_DIM);
  // qkv = x @ w_in  (bf16 out): 256x256 tiles, 16x12=192 blocks (%8==0)
  gemm_pipe<256, false><<<(S_LEN / 256) * (QKV_N / 256), 512, 0, stream>>>(
      x_bf, w_inT, qkv, nullptr, S_LEN, QKV_N, E_DIM, S_LEN / 256);
  // rope q,k ; transpose v
  rope_qk<<<(S_LEN * 1280) / 256, 256, 0, stream>>>(qkv, fcos, fsin, q_r, k_r);
  transpose_bf16<<<dim3(512 / 64, S_LEN / 64), 256, 0, stream>>>(qkv + 2560, v_t, QKV_N, S_LEN);
  // attention (QBLK=128, 4 waves x 32 rows, 32x32 MFMA)
  attn_kernel<<<dim3(S_LEN / 128, H_NUM), 256, 0, stream>>>(q_r, k_r, v_t, o_r);
  // out = o @ w_out  (fp32 out): 256x128 tiles, 16x16=256 blocks (full CU coverage)
  gemm_pipe<128, true><<<(S_LEN / 256) * (E_DIM / 128), 512, 0, stream>>>(
      o_r, w_outT, nullptr, out, S_LEN, E_DIM, E_DIM, S_LEN / 256);
}

// Round 8
// 202.846 us; speedup vs baseline: 1.1434x; 1.1434x over previous
//
#include <hip/hip_runtime.h>
#include <stdint.h>

using bf16x8 = __attribute__((ext_vector_type(8))) __bf16;
using f32x4  = __attribute__((ext_vector_type(4))) float;
using f32x16 = __attribute__((ext_vector_type(16))) float;
using u16x8  = __attribute__((ext_vector_type(8))) uint16_t;

#define S_LEN 4096
#define E_DIM 2048
#define D_DIM 128
#define H_NUM 16
#define G_NUM 4
#define QKV_N 3072
#define SCALE 0.08838834764831845f

__device__ inline float bf2f(uint16_t b) {
  union { uint32_t u; float f; } v; v.u = ((uint32_t)b) << 16; return v.f;
}
__device__ inline uint16_t f2bf(float f) {
  union { float f; uint32_t u; } v; v.f = f;
  uint32_t u = v.u + 0x7FFFu + ((v.u >> 16) & 1u);
  return (uint16_t)(u >> 16);
}
__device__ inline uint32_t packbf(float a, float b) {  // (lo=a, hi=b) round-half-up
  union { float f; uint32_t u; } x, y; x.f = a; y.f = b;
  return ((x.u + 0x8000u) >> 16) | ((y.u + 0x8000u) & 0xFFFF0000u);
}
__device__ inline void plswap(uint32_t& a, uint32_t& b) {
  asm volatile("v_permlane32_swap_b32 %0, %1" : "+v"(a), "+v"(b));
}
__device__ inline void gload_lds16(const void* g, void* l) {
  __builtin_amdgcn_global_load_lds((const __attribute__((address_space(1))) void*)g,
                                   (__attribute__((address_space(3))) void*)l, 16, 0, 0);
}

// ---------------- fp32 -> bf16 convert (8 elems/thread) ----------------
__global__ __launch_bounds__(256) void conv_f2b(const float* __restrict__ in,
                                                uint16_t* __restrict__ out) {
  const size_t i = ((size_t)blockIdx.x * 256 + threadIdx.x) * 8;
  float4 a = *(const float4*)(in + i);
  float4 b = *(const float4*)(in + i + 4);
  u16x8 o;
  o[0] = f2bf(a.x); o[1] = f2bf(a.y); o[2] = f2bf(a.z); o[3] = f2bf(a.w);
  o[4] = f2bf(b.x); o[5] = f2bf(b.y); o[6] = f2bf(b.z); o[7] = f2bf(b.w);
  *(u16x8*)(out + i) = o;
}

// ---------------- transpose fp32 -> bf16: out[c][r] = bf16(in[r][c]) ----------------
__global__ __launch_bounds__(256) void transpose_f2b(
    const float* __restrict__ in, uint16_t* __restrict__ out,
    int ldi, int ldo)
{
  __shared__ __align__(16) uint16_t tile[64][65];
  const int c0 = blockIdx.x * 64, r0 = blockIdx.y * 64;
  const int t = threadIdx.x;
#pragma unroll
  for (int i = 0; i < 16; ++i) {
    int idx = t + i * 256;
    int r = idx >> 6, c = idx & 63;
    tile[r][c] = f2bf(in[(size_t)(r0 + r) * ldi + c0 + c]);
  }
  __syncthreads();
#pragma unroll
  for (int i = 0; i < 16; ++i) {
    int idx = t + i * 256;
    int cc = idx >> 6, rr = idx & 63;
    out[(size_t)(c0 + cc) * ldo + r0 + rr] = tile[rr][cc];
  }
}

// ---------------- transpose bf16 -> bf16 (for V) ----------------
__global__ __launch_bounds__(256) void transpose_bf16(
    const uint16_t* __restrict__ in, uint16_t* __restrict__ out,
    int ldi, int ldo)
{
  __shared__ __align__(16) uint16_t tile[64][65];
  const int c0 = blockIdx.x * 64, r0 = blockIdx.y * 64;
  const int t = threadIdx.x;
#pragma unroll
  for (int i = 0; i < 16; ++i) {
    int idx = t + i * 256;
    int r = idx >> 6, c = idx & 63;
    tile[r][c] = in[(size_t)(r0 + r) * ldi + c0 + c];
  }
  __syncthreads();
#pragma unroll
  for (int i = 0; i < 16; ++i) {
    int idx = t + i * 256;
    int cc = idx >> 6, rr = idx & 63;
    out[(size_t)(c0 + cc) * ldo + r0 + rr] = tile[rr][cc];
  }
}

// ---------------- GEMM: C = A[M][K](bf16) * Bt[N][K]^T(bf16), f32 acc ----------------
// 128x128 tile, 4 waves. T3-minimum 2-phase: LDS double-buffer + counted
// vmcnt(4) (next tile's loads stay in flight across the barrier) + raw
// s_barrier. 32 KB LDS + launch_bounds(256,4) -> 4 blocks/CU.
__global__ __launch_bounds__(256, 4) void gemm_bt(
    const uint16_t* __restrict__ A, const uint16_t* __restrict__ Bt,
    uint16_t* __restrict__ Cb, float* __restrict__ Cf, int M, int N, int K, int nwgm)
{
  __shared__ __align__(16) uint16_t sA[2][128 * 32];
  __shared__ __align__(16) uint16_t sB[2][128 * 32];
  const int nwg = gridDim.x;
  const int id = ((int)blockIdx.x & 7) * (nwg >> 3) + ((int)blockIdx.x >> 3);  // XCD swizzle
  const int m0 = (id % nwgm) * 128, n0 = (id / nwgm) * 128;
  const int tid = threadIdx.x, w = tid >> 6, lane = tid & 63;
  const int lr = lane & 15, lq = lane >> 4;
  const int wr = w >> 1, wc = w & 1;

  f32x4 acc[4][4];
#pragma unroll
  for (int i = 0; i < 4; ++i)
#pragma unroll
    for (int j = 0; j < 4; ++j) acc[i][j] = (f32x4){0.f, 0.f, 0.f, 0.f};

  const int nk = K >> 5;
  const int colb = (lane & 3) << 4;           // byte col within 64B row
  const int rbase0 = w * 32 + (lane >> 2);    // staging row for this lane
  const char* gA0 = (const char*)A + ((size_t)(m0 + rbase0) * K) * 2 + colb;
  const char* gA1 = (const char*)A + ((size_t)(m0 + rbase0 + 16) * K) * 2 + colb;
  const char* gB0 = (const char*)Bt + ((size_t)(n0 + rbase0) * K) * 2 + colb;
  const char* gB1 = (const char*)Bt + ((size_t)(n0 + rbase0 + 16) * K) * 2 + colb;
  const int d0 = (w * 2) * 1024;              // LDS byte offsets within a buffer
  const int d1 = (w * 2 + 1) * 1024;

#define GS(buf, kt)                                                     \
  {                                                                     \
    const size_t _ko = (size_t)(kt) * 64;                               \
    gload_lds16(gA0 + _ko, (char*)sA + (buf) * 8192 + d0);              \
    gload_lds16(gA1 + _ko, (char*)sA + (buf) * 8192 + d1);              \
    gload_lds16(gB0 + _ko, (char*)sB + (buf) * 8192 + d0);              \
    gload_lds16(gB1 + _ko, (char*)sB + (buf) * 8192 + d1);              \
  }

  GS(0, 0)
  for (int kt = 0; kt < nk; ++kt) {
    const int buf = kt & 1;
    if (kt + 1 < nk) {
      GS(buf ^ 1, kt + 1)
      asm volatile("s_waitcnt vmcnt(4)" ::: "memory");  // buf resident; next in flight
    } else {
      asm volatile("s_waitcnt vmcnt(0)" ::: "memory");
    }
    __builtin_amdgcn_s_barrier();                       // all waves' buf loads landed
    asm volatile("" ::: "memory");

    const uint16_t* Ab = sA[buf];
    const uint16_t* Bb = sB[buf];
    bf16x8 af[4], bfj[4];
#pragma unroll
    for (int i = 0; i < 4; ++i) af[i] = *(const bf16x8*)(Ab + (wr * 64 + i * 16 + lr) * 32 + lq * 8);
#pragma unroll
    for (int j = 0; j < 4; ++j) bfj[j] = *(const bf16x8*)(Bb + (wc * 64 + j * 16 + lr) * 32 + lq * 8);
    __builtin_amdgcn_s_setprio(1);
#pragma unroll
    for (int i = 0; i < 4; ++i)
#pragma unroll
      for (int j = 0; j < 4; ++j)
        acc[i][j] = __builtin_amdgcn_mfma_f32_16x16x32_bf16(af[i], bfj[j], acc[i][j], 0, 0, 0);
    __builtin_amdgcn_s_setprio(0);

    __builtin_amdgcn_s_barrier();                       // reads done before next overwrite
    asm volatile("" ::: "memory");
  }
#undef GS

  if (Cf) {
#pragma unroll
    for (int i = 0; i < 4; ++i)
#pragma unroll
      for (int j = 0; j < 4; ++j)
#pragma unroll
        for (int r = 0; r < 4; ++r)
          Cf[(size_t)(m0 + wr * 64 + i * 16 + lq * 4 + r) * N + n0 + wc * 64 + j * 16 + lr] =
              acc[i][j][r];
  } else {
#pragma unroll
    for (int i = 0; i < 4; ++i)
#pragma unroll
      for (int j = 0; j < 4; ++j)
#pragma unroll
        for (int r = 0; r < 4; ++r)
          Cb[(size_t)(m0 + wr * 64 + i * 16 + lq * 4 + r) * N + n0 + wc * 64 + j * 16 + lr] =
              f2bf(acc[i][j][r]);
  }
}

// ---------------- RoPE + rearrange for q,k (cos/sin are fp32) ----------------
__global__ __launch_bounds__(256) void rope_qk(
    const uint16_t* __restrict__ qkv, const float* __restrict__ cosb,
    const float* __restrict__ sinb, uint16_t* __restrict__ q_r, uint16_t* __restrict__ k_r)
{
  const int idx = blockIdx.x * 256 + threadIdx.x;  // < 4096*1280
  const int s = idx / 1280;
  const int pp = idx - s * 1280;
  const int c0 = pp << 1;
  const uint32_t xp = *(const uint32_t*)(qkv + (size_t)s * QKV_N + c0);
  const float xe = bf2f((uint16_t)xp), xo = bf2f((uint16_t)(xp >> 16));
  const int dloc = c0 & 127;
  const int dd = dloc >> 1;
  const float cf = cosb[s * 64 + dd];
  const float sf = sinb[s * 64 + dd];
  float oe = xe * cf - xo * sf;
  float oo = xe * sf + xo * cf;
  uint16_t* dst;
  if (c0 < E_DIM) {
    oe *= SCALE; oo *= SCALE;                 // fold 1/sqrt(D) into q
    const int h = c0 >> 7;
    dst = q_r + ((size_t)h * S_LEN + s) * D_DIM + dloc;
  } else {
    const int g = (c0 - E_DIM) >> 7;
    dst = k_r + ((size_t)g * S_LEN + s) * D_DIM + dloc;
  }
  *(uint32_t*)dst = (uint32_t)f2bf(oe) | ((uint32_t)f2bf(oo) << 16);
}

// ---------------- flash attention, window [p-1024, p] ----------------
// 32x32x16 MFMA path: 4 waves x 32 q-rows (QBLK=128). Swapped QK^T puts the
// softmax row on lane&31 (1-hop reduce); P->PV A-frags built in-register via
// cvt-pack + v_permlane32_swap_b32 (zero LDS). 2x FLOP per LDS byte vs 16x16.
__global__ __launch_bounds__(256, 2) void attn_kernel(
    const uint16_t* __restrict__ q_r, const uint16_t* __restrict__ k_r,
    const uint16_t* __restrict__ v_t, uint16_t* __restrict__ o_r)
{
  __shared__ __align__(16) uint16_t sK[2][64 * 128];   // [key][d], swizzled
  __shared__ __align__(16) uint16_t sVT[2][128 * 64];  // [d][key], swizzled
  const int h = blockIdx.y, g = h >> 2;
  const int q0 = blockIdx.x * 128;
  const int tid = threadIdx.x, w = tid >> 6, lane = tid & 63;
  const int lc = lane & 31, hi = lane >> 5;
  const int pmin = q0 + w * 32, pmax = pmin + 31;
  const int pq = pmin + lc;       // this lane's softmax row (q index)

  bf16x8 aq[8];
  {
    const uint16_t* qb = q_r + ((size_t)h * S_LEN + pq) * D_DIM + hi * 8;
#pragma unroll
    for (int ks = 0; ks < 8; ++ks) aq[ks] = *(const bf16x8*)(qb + ks * 16);
  }
  f32x16 accO[4];
#pragma unroll
  for (int dt = 0; dt < 4; ++dt) accO[dt] = 0;
  float M = -1e30f, L = 0.f;

  const int jstart = (q0 >= 1024) ? (q0 - 1024) : 0;
  const int nt = (q0 + 128 - jstart) >> 6;
  const char* kb = (const char*)(k_r + ((size_t)g * S_LEN + jstart) * D_DIM);
  const char* vb = (const char*)(v_t + (size_t)g * D_DIM * S_LEN + jstart);

  const int kc_row = lane >> 4;                         // row within 4-row K chunk
  const int k_col0 = (lane & 15) << 4;                  // linear byte col (K)
  const int v_scol = (((lane & 7) ^ (lane >> 3)) << 4); // swizzled byte col (V)
  const int v_row = lane >> 3;                          // row within 8-row V chunk

#define STAGE_KV(buf, tt)                                                              \
  {                                                                                    \
    const char* kt_ = kb + (size_t)(tt) * 16384;                                       \
    const char* vt_ = vb + (size_t)(tt) * 128;                                         \
    _Pragma("unroll")                                                                  \
    for (int it = 0; it < 4; ++it) {                                                   \
      const int c = w * 4 + it;                                                        \
      const int krow = c * 4 + kc_row;                                                 \
      const int kscol = k_col0 ^ ((krow & 7) << 4);                                    \
      gload_lds16(kt_ + krow * 256 + kscol, (char*)sK[buf] + c * 1024 + lane * 16);    \
      const int vrow = c * 8 + v_row;                                                  \
      gload_lds16(vt_ + (size_t)vrow * (S_LEN * 2) + v_scol,                           \
                  (char*)sVT[buf] + c * 1024 + lane * 16);                             \
    }                                                                                  \
  }

  STAGE_KV(0, 0)
  asm volatile("s_waitcnt vmcnt(0)" ::: "memory");
  __syncthreads();

  for (int t = 0; t < nt; ++t) {
    const int b = t & 1;
    if (t + 1 < nt) STAGE_KV(b ^ 1, t + 1)
    const int j0 = jstart + t * 64;
    const uint16_t* Kb = sK[b];
    const uint16_t* Vb = sVT[b];

    const bool active = (j0 <= pmax) && (j0 + 63 + 1024 >= pmin);
    if (active) {
      f32x16 accS[2];
      accS[0] = 0; accS[1] = 0;
      __builtin_amdgcn_s_setprio(1);
#pragma unroll
      for (int rt = 0; rt < 2; ++rt) {
        const int krow = rt * 32 + lc;
        const int ksw = (krow & 7) << 3;
#pragma unroll
        for (int ks = 0; ks < 8; ++ks) {
          bf16x8 ak = *(const bf16x8*)(Kb + krow * 128 + ((ks * 16 + hi * 8) ^ ksw));
          accS[rt] = __builtin_amdgcn_mfma_f32_32x32x16_bf16(ak, aq[ks], accS[rt], 0, 0, 0);
        }
      }
      __builtin_amdgcn_s_setprio(0);

      const bool need_mask = (j0 + 63 > pmin) || (j0 < pmax - 1024);
      if (need_mask) {
#pragma unroll
        for (int rt = 0; rt < 2; ++rt)
#pragma unroll
          for (int c = 0; c < 16; ++c) {
            const int j = j0 + rt * 32 + (c & 3) + 8 * (c >> 2) + 4 * hi;
            const bool ok = (j <= pq) && (j + 1024 >= pq);
            accS[rt][c] = ok ? accS[rt][c] : -1e30f;
          }
      }

      float mx = accS[0][0];
#pragma unroll
      for (int rt = 0; rt < 2; ++rt)
#pragma unroll
        for (int c = 0; c < 16; ++c) mx = fmaxf(mx, accS[rt][c]);
      mx = fmaxf(mx, __shfl_xor(mx, 32));

      if (__any(mx > M + 4.f)) {
        const float Mn = fmaxf(M, mx);
        const float al = __expf(M - Mn);
        M = Mn;
        L *= al;
        float alr[16];
#pragma unroll
        for (int c = 0; c < 16; ++c) alr[c] = __shfl(al, (c & 3) + 8 * (c >> 2) + 4 * hi);
#pragma unroll
        for (int dt = 0; dt < 4; ++dt)
#pragma unroll
          for (int c = 0; c < 16; ++c) accO[dt][c] *= alr[c];
      }

      float rs = 0.f;
#pragma unroll
      for (int rt = 0; rt < 2; ++rt)
#pragma unroll
        for (int c = 0; c < 16; ++c) {
          const float pv = __expf(accS[rt][c] - M);
          accS[rt][c] = pv;
          rs += pv;
        }
      rs += __shfl_xor(rs, 32);
      L += rs;

      __builtin_amdgcn_s_setprio(1);
#pragma unroll
      for (int rt = 0; rt < 2; ++rt) {
        uint32_t wv[8];
#pragma unroll
        for (int jj = 0; jj < 8; ++jj)
          wv[jj] = packbf(accS[rt][2 * jj], accS[rt][2 * jj + 1]);
        plswap(wv[0], wv[2]); plswap(wv[1], wv[3]);
        plswap(wv[4], wv[6]); plswap(wv[5], wv[7]);
#pragma unroll
        for (int sub = 0; sub < 2; ++sub) {
          union { uint32_t u[4]; bf16x8 v; } ap;
          ap.u[0] = wv[sub * 4 + 0]; ap.u[1] = wv[sub * 4 + 1];
          ap.u[2] = wv[sub * 4 + 2]; ap.u[3] = wv[sub * 4 + 3];
          const int kbase = rt * 32 + sub * 16 + hi * 8;
#pragma unroll
          for (int dt = 0; dt < 4; ++dt) {
            const int vrow = dt * 32 + lc;
            bf16x8 bv = *(const bf16x8*)(Vb + vrow * 64 + (kbase ^ ((vrow & 7) << 3)));
            accO[dt] = __builtin_amdgcn_mfma_f32_32x32x16_bf16(ap.v, bv, accO[dt], 0, 0, 0);
          }
        }
      }
      __builtin_amdgcn_s_setprio(0);
    }

    asm volatile("s_waitcnt vmcnt(0)" ::: "memory");
    __syncthreads();
  }

  const float ivl = 1.f / L;
  float il[16];
#pragma unroll
  for (int c = 0; c < 16; ++c) il[c] = __shfl(ivl, (c & 3) + 8 * (c >> 2) + 4 * hi);
#pragma unroll
  for (int dt = 0; dt < 4; ++dt)
#pragma unroll
    for (int c = 0; c < 16; ++c) {
      const int p = pmin + (c & 3) + 8 * (c >> 2) + 4 * hi;
      o_r[(size_t)p * E_DIM + h * D_DIM + dt * 32 + lc] = f2bf(accO[dt][c] * il[c]);
    }
}

extern "C" void kernel_launch(void* const* d_in, const int* in_sizes, int n_in,
                              void* d_out, int out_size, void* d_ws, size_t ws_size,
                              hipStream_t stream) {
  const float* x     = (const float*)d_in[0];
  const float* fcos  = (const float*)d_in[1];
  const float* fsin  = (const float*)d_in[2];
  const float* w_in  = (const float*)d_in[3];
  const float* w_out = (const float*)d_in[4];
  float* out = (float*)d_out;

  char* ws = (char*)d_ws;
  size_t off = 0;
  uint16_t* w_inT  = (uint16_t*)(ws + off); off += (size_t)QKV_N * E_DIM * 2;      // 3072x2048 bf16
  uint16_t* w_outT = (uint16_t*)(ws + off); off += (size_t)E_DIM * E_DIM * 2;      // 2048x2048 bf16
  uint16_t* qkv    = (uint16_t*)(ws + off); off += (size_t)S_LEN * QKV_N * 2;      // 4096x3072 bf16
  uint16_t* q_r    = (uint16_t*)(ws + off); off += (size_t)H_NUM * S_LEN * D_DIM * 2;
  uint16_t* k_r    = (uint16_t*)(ws + off); off += (size_t)G_NUM * S_LEN * D_DIM * 2;
  uint16_t* v_t    = (uint16_t*)(ws + off); off += (size_t)G_NUM * D_DIM * S_LEN * 2;
  uint16_t* o_r    = (uint16_t*)(ws + off); off += (size_t)S_LEN * E_DIM * 2;
  // x_bf aliases o_r: x_bf is consumed by gemm1 before attn writes o_r (stream-ordered).
  uint16_t* x_bf   = o_r;  // 4096x2048 bf16, same size as o_r

  // edge conversions: fp32 -> bf16
  conv_f2b<<<(S_LEN * E_DIM) / (256 * 8), 256, 0, stream>>>(x, x_bf);
  transpose_f2b<<<dim3(QKV_N / 64, E_DIM / 64), 256, 0, stream>>>(w_in, w_inT, QKV_N, E_DIM);
  transpose_f2b<<<dim3(E_DIM / 64, E_DIM / 64), 256, 0, stream>>>(w_out, w_outT, E_DIM, E_DIM);
  // qkv = x @ w_in  (bf16 out); grid flattened, %8==0 for XCD swizzle
  gemm_bt<<<(S_LEN / 128) * (QKV_N / 128), 256, 0, stream>>>(x_bf, w_inT, qkv, nullptr,
                                                             S_LEN, QKV_N, E_DIM, S_LEN / 128);
  // rope q,k ; transpose v
  rope_qk<<<(S_LEN * 1280) / 256, 256, 0, stream>>>(qkv, fcos, fsin, q_r, k_r);
  transpose_bf16<<<dim3(512 / 64, S_LEN / 64), 256, 0, stream>>>(qkv + 2560, v_t, QKV_N, S_LEN);
  // attention (QBLK=128, 4 waves x 32 rows, 32x32 MFMA)
  attn_kernel<<<dim3(S_LEN / 128, H_NUM), 256, 0, stream>>>(q_r, k_r, v_t, o_r);
  // out = o @ w_out  (fp32 out)
  gemm_bt<<<(S_LEN / 128) * (E_DIM / 128), 256, 0, stream>>>(o_r, w_outT, nullptr, out,
                                                             S_LEN, E_DIM, E_DIM, S_LEN / 128);
}

// Round 9
// 192.157 us; speedup vs baseline: 1.2070x; 1.0556x over previous
//
#include <hip/hip_runtime.h>
#include <stdint.h>

using bf16x8 = __attribute__((ext_vector_type(8))) __bf16;
using f32x4  = __attribute__((ext_vector_type(4))) float;
using f32x16 = __attribute__((ext_vector_type(16))) float;
using u16x8  = __attribute__((ext_vector_type(8))) uint16_t;

#define S_LEN 4096
#define E_DIM 2048
#define D_DIM 128
#define H_NUM 16
#define G_NUM 4
#define QKV_N 3072
#define SCALE 0.08838834764831845f

__device__ inline float bf2f(uint16_t b) {
  union { uint32_t u; float f; } v; v.u = ((uint32_t)b) << 16; return v.f;
}
__device__ inline uint16_t f2bf(float f) {
  union { float f; uint32_t u; } v; v.f = f;
  uint32_t u = v.u + 0x7FFFu + ((v.u >> 16) & 1u);
  return (uint16_t)(u >> 16);
}
__device__ inline uint32_t packbf(float a, float b) {  // (lo=a, hi=b) round-half-up
  union { float f; uint32_t u; } x, y; x.f = a; y.f = b;
  return ((x.u + 0x8000u) >> 16) | ((y.u + 0x8000u) & 0xFFFF0000u);
}
__device__ inline void plswap(uint32_t& a, uint32_t& b) {
  asm volatile("v_permlane32_swap_b32 %0, %1" : "+v"(a), "+v"(b));
}
__device__ inline void gload_lds16(const void* g, void* l) {
  __builtin_amdgcn_global_load_lds((const __attribute__((address_space(1))) void*)g,
                                   (__attribute__((address_space(3))) void*)l, 16, 0, 0);
}

// ---------------- fp32 -> bf16 convert (8 elems/thread) ----------------
__global__ __launch_bounds__(256) void conv_f2b(const float* __restrict__ in,
                                                uint16_t* __restrict__ out) {
  const size_t i = ((size_t)blockIdx.x * 256 + threadIdx.x) * 8;
  float4 a = *(const float4*)(in + i);
  float4 b = *(const float4*)(in + i + 4);
  u16x8 o;
  o[0] = f2bf(a.x); o[1] = f2bf(a.y); o[2] = f2bf(a.z); o[3] = f2bf(a.w);
  o[4] = f2bf(b.x); o[5] = f2bf(b.y); o[6] = f2bf(b.z); o[7] = f2bf(b.w);
  *(u16x8*)(out + i) = o;
}

// ---------------- transpose fp32 -> bf16: out[c][r] = bf16(in[r][c]) ----------------
__global__ __launch_bounds__(256) void transpose_f2b(
    const float* __restrict__ in, uint16_t* __restrict__ out,
    int ldi, int ldo)
{
  __shared__ __align__(16) uint16_t tile[64][65];
  const int c0 = blockIdx.x * 64, r0 = blockIdx.y * 64;
  const int t = threadIdx.x;
#pragma unroll
  for (int i = 0; i < 16; ++i) {
    int idx = t + i * 256;
    int r = idx >> 6, c = idx & 63;
    tile[r][c] = f2bf(in[(size_t)(r0 + r) * ldi + c0 + c]);
  }
  __syncthreads();
#pragma unroll
  for (int i = 0; i < 16; ++i) {
    int idx = t + i * 256;
    int cc = idx >> 6, rr = idx & 63;
    out[(size_t)(c0 + cc) * ldo + r0 + rr] = tile[rr][cc];
  }
}

// ================= shared GEMM main-loop pieces (2-phase, swizzled) =================
// LDS bank-group derivation: fragment read at row rl, granule slot s -> group
// (rl&1)*4 + s.  Linear s==lq gives 8-way conflict; s = lq ^ ((rl>>1)&3) makes
// all 8 groups distinct across lr=0..7 (wave64 b128 minimum).  Staged via
// pre-swizzled GLOBAL chunk (lane&3)^((lane>>3)&3); valid for both row-halves
// since (rl+16)>>1 preserves &3.

#define GEMM_PROLOGUE(A_, Bt_, K_)                                                \
  const int tid = threadIdx.x, w = tid >> 6, lane = tid & 63;                     \
  const int lr = lane & 15, lq = lane >> 4;                                       \
  const int wr = w >> 1, wc = w & 1;                                              \
  f32x4 acc[4][4];                                                                \
  _Pragma("unroll") for (int i = 0; i < 4; ++i)                                   \
  _Pragma("unroll") for (int j = 0; j < 4; ++j) acc[i][j] = (f32x4){0.f,0.f,0.f,0.f}; \
  const int nk = (K_) >> 5;                                                       \
  const int colb = ((lane & 3) ^ ((lane >> 3) & 3)) << 4;                         \
  const int rbase0 = w * 32 + (lane >> 2);                                        \
  const char* gA0 = (const char*)(A_) + ((size_t)(m0 + rbase0) * (K_)) * 2 + colb;      \
  const char* gA1 = (const char*)(A_) + ((size_t)(m0 + rbase0 + 16) * (K_)) * 2 + colb; \
  const char* gB0 = (const char*)(Bt_) + ((size_t)(n0 + rbase0) * (K_)) * 2 + colb;     \
  const char* gB1 = (const char*)(Bt_) + ((size_t)(n0 + rbase0 + 16) * (K_)) * 2 + colb;\
  const int d0 = (w * 2) * 1024;                                                  \
  const int d1 = (w * 2 + 1) * 1024;                                              \
  const int sw = (lq ^ ((lr >> 1) & 3)) << 3;  /* element offset of swizzled granule */

#define GS(buf, kt)                                                     \
  {                                                                     \
    const size_t _ko = (size_t)(kt) * 64;                               \
    gload_lds16(gA0 + _ko, (char*)sA + (buf) * 8192 + d0);              \
    gload_lds16(gA1 + _ko, (char*)sA + (buf) * 8192 + d1);              \
    gload_lds16(gB0 + _ko, (char*)sB + (buf) * 8192 + d0);              \
    gload_lds16(gB1 + _ko, (char*)sB + (buf) * 8192 + d1);              \
  }

#define GEMM_MAINLOOP                                                            \
  GS(0, 0)                                                                       \
  for (int kt = 0; kt < nk; ++kt) {                                              \
    const int buf = kt & 1;                                                      \
    if (kt + 1 < nk) {                                                           \
      GS(buf ^ 1, kt + 1)                                                        \
      asm volatile("s_waitcnt vmcnt(4)" ::: "memory");                           \
    } else {                                                                     \
      asm volatile("s_waitcnt vmcnt(0)" ::: "memory");                           \
    }                                                                            \
    __builtin_amdgcn_s_barrier();                                                \
    asm volatile("" ::: "memory");                                               \
    const uint16_t* Ab = sA[buf];                                                \
    const uint16_t* Bb = sB[buf];                                                \
    bf16x8 af[4], bfj[4];                                                        \
    _Pragma("unroll") for (int i = 0; i < 4; ++i)                                \
      af[i] = *(const bf16x8*)(Ab + (wr * 64 + i * 16 + lr) * 32 + sw);          \
    _Pragma("unroll") for (int j = 0; j < 4; ++j)                                \
      bfj[j] = *(const bf16x8*)(Bb + (wc * 64 + j * 16 + lr) * 32 + sw);         \
    __builtin_amdgcn_s_setprio(1);                                               \
    _Pragma("unroll") for (int i = 0; i < 4; ++i)                                \
    _Pragma("unroll") for (int j = 0; j < 4; ++j)                                \
      acc[i][j] = __builtin_amdgcn_mfma_f32_16x16x32_bf16(af[i], bfj[j], acc[i][j], 0, 0, 0); \
    __builtin_amdgcn_s_setprio(0);                                               \
    __builtin_amdgcn_s_barrier();                                                \
    asm volatile("" ::: "memory");                                               \
  }

// ---------------- GEMM (generic): C = A * Bt^T, fp32 or bf16 out ----------------
__global__ __launch_bounds__(256, 4) void gemm_bt(
    const uint16_t* __restrict__ A, const uint16_t* __restrict__ Bt,
    uint16_t* __restrict__ Cb, float* __restrict__ Cf, int M, int N, int K, int nwgm)
{
  __shared__ __align__(16) uint16_t sA[2][128 * 32];
  __shared__ __align__(16) uint16_t sB[2][128 * 32];
  const int nwg = gridDim.x;
  const int id = ((int)blockIdx.x & 7) * (nwg >> 3) + ((int)blockIdx.x >> 3);
  const int m0 = (id % nwgm) * 128, n0 = (id / nwgm) * 128;
  GEMM_PROLOGUE(A, Bt, K)
  GEMM_MAINLOOP

  if (Cf) {
#pragma unroll
    for (int i = 0; i < 4; ++i)
#pragma unroll
      for (int j = 0; j < 4; ++j)
#pragma unroll
        for (int r = 0; r < 4; ++r)
          Cf[(size_t)(m0 + wr * 64 + i * 16 + lq * 4 + r) * N + n0 + wc * 64 + j * 16 + lr] =
              acc[i][j][r];
  } else {
#pragma unroll
    for (int i = 0; i < 4; ++i)
#pragma unroll
      for (int j = 0; j < 4; ++j)
#pragma unroll
        for (int r = 0; r < 4; ++r)
          Cb[(size_t)(m0 + wr * 64 + i * 16 + lq * 4 + r) * N + n0 + wc * 64 + j * 16 + lr] =
              f2bf(acc[i][j][r]);
  }
}

// ---------------- GEMM1 + fused RoPE/split epilogue ----------------
// N=3072: tiles are 128-aligned = exactly one head. q tiles (n0<2048) and
// k tiles (2048..2559) rope in-register (partner via shfl_xor(1)) and write
// q_r/k_r; v tiles (>=2560) write transposed into v_t. No qkv buffer.
__global__ __launch_bounds__(256, 4) void gemm_qkv(
    const uint16_t* __restrict__ A, const uint16_t* __restrict__ Bt,
    const float* __restrict__ cosb, const float* __restrict__ sinb,
    uint16_t* __restrict__ q_r, uint16_t* __restrict__ k_r,
    uint16_t* __restrict__ v_t, int K, int nwgm)
{
  __shared__ __align__(16) uint16_t sA[2][128 * 32];
  __shared__ __align__(16) uint16_t sB[2][128 * 32];
  const int nwg = gridDim.x;
  const int id = ((int)blockIdx.x & 7) * (nwg >> 3) + ((int)blockIdx.x >> 3);
  const int m0 = (id % nwgm) * 128, n0 = (id / nwgm) * 128;
  GEMM_PROLOGUE(A, Bt, K)
  GEMM_MAINLOOP

  if (n0 < 2560) {  // q or k: rope
    const bool isq = (n0 < E_DIM);
    uint16_t* dstb = isq ? (q_r + (size_t)(n0 >> 7) * S_LEN * D_DIM)
                         : (k_r + (size_t)((n0 - E_DIM) >> 7) * S_LEN * D_DIM);
    const bool odd = (lr & 1);
#pragma unroll
    for (int i = 0; i < 4; ++i)
#pragma unroll
      for (int j = 0; j < 4; ++j) {
        const int d = wc * 64 + j * 16 + lr;
        const int dd = d >> 1;
#pragma unroll
        for (int r = 0; r < 4; ++r) {
          const int s = m0 + wr * 64 + i * 16 + lq * 4 + r;
          const float v = acc[i][j][r];
          const float p = __shfl_xor(v, 1);
          const float cf = cosb[s * 64 + dd];
          const float sf = sinb[s * 64 + dd];
          float o = odd ? (p * sf + v * cf) : (v * cf - p * sf);
          if (isq) o *= SCALE;
          dstb[(size_t)s * D_DIM + d] = f2bf(o);
        }
      }
  } else {  // v: transposed store v_t[g][d][s]
    uint16_t* dstb = v_t + (size_t)((n0 - 2560) >> 7) * D_DIM * S_LEN;
#pragma unroll
    for (int i = 0; i < 4; ++i)
#pragma unroll
      for (int j = 0; j < 4; ++j) {
        const int d = wc * 64 + j * 16 + lr;
#pragma unroll
        for (int r = 0; r < 4; ++r) {
          const int s = m0 + wr * 64 + i * 16 + lq * 4 + r;
          dstb[(size_t)d * S_LEN + s] = f2bf(acc[i][j][r]);
        }
      }
  }
}

// ---------------- flash attention, window [p-1024, p] ----------------
// 32x32x16 MFMA path: 4 waves x 32 q-rows (QBLK=128). Swapped QK^T puts the
// softmax row on lane&31 (1-hop reduce); P->PV A-frags built in-register via
// cvt-pack + v_permlane32_swap_b32 (zero LDS). 2x FLOP per LDS byte vs 16x16.
__global__ __launch_bounds__(256, 2) void attn_kernel(
    const uint16_t* __restrict__ q_r, const uint16_t* __restrict__ k_r,
    const uint16_t* __restrict__ v_t, uint16_t* __restrict__ o_r)
{
  __shared__ __align__(16) uint16_t sK[2][64 * 128];   // [key][d], swizzled
  __shared__ __align__(16) uint16_t sVT[2][128 * 64];  // [d][key], swizzled
  const int h = blockIdx.y, g = h >> 2;
  const int q0 = blockIdx.x * 128;
  const int tid = threadIdx.x, w = tid >> 6, lane = tid & 63;
  const int lc = lane & 31, hi = lane >> 5;
  const int pmin = q0 + w * 32, pmax = pmin + 31;
  const int pq = pmin + lc;       // this lane's softmax row (q index)

  bf16x8 aq[8];
  {
    const uint16_t* qb = q_r + ((size_t)h * S_LEN + pq) * D_DIM + hi * 8;
#pragma unroll
    for (int ks = 0; ks < 8; ++ks) aq[ks] = *(const bf16x8*)(qb + ks * 16);
  }
  f32x16 accO[4];
#pragma unroll
  for (int dt = 0; dt < 4; ++dt) accO[dt] = 0;
  float M = -1e30f, L = 0.f;

  const int jstart = (q0 >= 1024) ? (q0 - 1024) : 0;
  const int nt = (q0 + 128 - jstart) >> 6;
  const char* kb = (const char*)(k_r + ((size_t)g * S_LEN + jstart) * D_DIM);
  const char* vb = (const char*)(v_t + (size_t)g * D_DIM * S_LEN + jstart);

  const int kc_row = lane >> 4;                         // row within 4-row K chunk
  const int k_col0 = (lane & 15) << 4;                  // linear byte col (K)
  const int v_scol = (((lane & 7) ^ (lane >> 3)) << 4); // swizzled byte col (V)
  const int v_row = lane >> 3;                          // row within 8-row V chunk

#define STAGE_KV(buf, tt)                                                              \
  {                                                                                    \
    const char* kt_ = kb + (size_t)(tt) * 16384;                                       \
    const char* vt_ = vb + (size_t)(tt) * 128;                                         \
    _Pragma("unroll")                                                                  \
    for (int it = 0; it < 4; ++it) {                                                   \
      const int c = w * 4 + it;                                                        \
      const int krow = c * 4 + kc_row;                                                 \
      const int kscol = k_col0 ^ ((krow & 7) << 4);                                    \
      gload_lds16(kt_ + krow * 256 + kscol, (char*)sK[buf] + c * 1024 + lane * 16);    \
      const int vrow = c * 8 + v_row;                                                  \
      gload_lds16(vt_ + (size_t)vrow * (S_LEN * 2) + v_scol,                           \
                  (char*)sVT[buf] + c * 1024 + lane * 16);                             \
    }                                                                                  \
  }

  STAGE_KV(0, 0)
  asm volatile("s_waitcnt vmcnt(0)" ::: "memory");
  __syncthreads();

  for (int t = 0; t < nt; ++t) {
    const int b = t & 1;
    if (t + 1 < nt) STAGE_KV(b ^ 1, t + 1)
    const int j0 = jstart + t * 64;
    const uint16_t* Kb = sK[b];
    const uint16_t* Vb = sVT[b];

    const bool active = (j0 <= pmax) && (j0 + 63 + 1024 >= pmin);
    if (active) {
      f32x16 accS[2];
      accS[0] = 0; accS[1] = 0;
      __builtin_amdgcn_s_setprio(1);
#pragma unroll
      for (int rt = 0; rt < 2; ++rt) {
        const int krow = rt * 32 + lc;
        const int ksw = (krow & 7) << 3;
#pragma unroll
        for (int ks = 0; ks < 8; ++ks) {
          bf16x8 ak = *(const bf16x8*)(Kb + krow * 128 + ((ks * 16 + hi * 8) ^ ksw));
          accS[rt] = __builtin_amdgcn_mfma_f32_32x32x16_bf16(ak, aq[ks], accS[rt], 0, 0, 0);
        }
      }
      __builtin_amdgcn_s_setprio(0);

      const bool need_mask = (j0 + 63 > pmin) || (j0 < pmax - 1024);
      if (need_mask) {
#pragma unroll
        for (int rt = 0; rt < 2; ++rt)
#pragma unroll
          for (int c = 0; c < 16; ++c) {
            const int j = j0 + rt * 32 + (c & 3) + 8 * (c >> 2) + 4 * hi;
            const bool ok = (j <= pq) && (j + 1024 >= pq);
            accS[rt][c] = ok ? accS[rt][c] : -1e30f;
          }
      }

      float mx = accS[0][0];
#pragma unroll
      for (int rt = 0; rt < 2; ++rt)
#pragma unroll
        for (int c = 0; c < 16; ++c) mx = fmaxf(mx, accS[rt][c]);
      mx = fmaxf(mx, __shfl_xor(mx, 32));

      if (__any(mx > M + 4.f)) {
        const float Mn = fmaxf(M, mx);
        const float al = __expf(M - Mn);
        M = Mn;
        L *= al;
        float alr[16];
#pragma unroll
        for (int c = 0; c < 16; ++c) alr[c] = __shfl(al, (c & 3) + 8 * (c >> 2) + 4 * hi);
#pragma unroll
        for (int dt = 0; dt < 4; ++dt)
#pragma unroll
          for (int c = 0; c < 16; ++c) accO[dt][c] *= alr[c];
      }

      float rs = 0.f;
#pragma unroll
      for (int rt = 0; rt < 2; ++rt)
#pragma unroll
        for (int c = 0; c < 16; ++c) {
          const float pv = __expf(accS[rt][c] - M);
          accS[rt][c] = pv;
          rs += pv;
        }
      rs += __shfl_xor(rs, 32);
      L += rs;

      __builtin_amdgcn_s_setprio(1);
#pragma unroll
      for (int rt = 0; rt < 2; ++rt) {
        uint32_t wv[8];
#pragma unroll
        for (int jj = 0; jj < 8; ++jj)
          wv[jj] = packbf(accS[rt][2 * jj], accS[rt][2 * jj + 1]);
        plswap(wv[0], wv[2]); plswap(wv[1], wv[3]);
        plswap(wv[4], wv[6]); plswap(wv[5], wv[7]);
#pragma unroll
        for (int sub = 0; sub < 2; ++sub) {
          union { uint32_t u[4]; bf16x8 v; } ap;
          ap.u[0] = wv[sub * 4 + 0]; ap.u[1] = wv[sub * 4 + 1];
          ap.u[2] = wv[sub * 4 + 2]; ap.u[3] = wv[sub * 4 + 3];
          const int kbase = rt * 32 + sub * 16 + hi * 8;
#pragma unroll
          for (int dt = 0; dt < 4; ++dt) {
            const int vrow = dt * 32 + lc;
            bf16x8 bv = *(const bf16x8*)(Vb + vrow * 64 + (kbase ^ ((vrow & 7) << 3)));
            accO[dt] = __builtin_amdgcn_mfma_f32_32x32x16_bf16(ap.v, bv, accO[dt], 0, 0, 0);
          }
        }
      }
      __builtin_amdgcn_s_setprio(0);
    }

    asm volatile("s_waitcnt vmcnt(0)" ::: "memory");
    __syncthreads();
  }

  const float ivl = 1.f / L;
  float il[16];
#pragma unroll
  for (int c = 0; c < 16; ++c) il[c] = __shfl(ivl, (c & 3) + 8 * (c >> 2) + 4 * hi);
#pragma unroll
  for (int dt = 0; dt < 4; ++dt)
#pragma unroll
    for (int c = 0; c < 16; ++c) {
      const int p = pmin + (c & 3) + 8 * (c >> 2) + 4 * hi;
      o_r[(size_t)p * E_DIM + h * D_DIM + dt * 32 + lc] = f2bf(accO[dt][c] * il[c]);
    }
}

extern "C" void kernel_launch(void* const* d_in, const int* in_sizes, int n_in,
                              void* d_out, int out_size, void* d_ws, size_t ws_size,
                              hipStream_t stream) {
  const float* x     = (const float*)d_in[0];
  const float* fcos  = (const float*)d_in[1];
  const float* fsin  = (const float*)d_in[2];
  const float* w_in  = (const float*)d_in[3];
  const float* w_out = (const float*)d_in[4];
  float* out = (float*)d_out;

  char* ws = (char*)d_ws;
  size_t off = 0;
  uint16_t* w_inT  = (uint16_t*)(ws + off); off += (size_t)QKV_N * E_DIM * 2;      // 3072x2048 bf16
  uint16_t* w_outT = (uint16_t*)(ws + off); off += (size_t)E_DIM * E_DIM * 2;      // 2048x2048 bf16
  uint16_t* q_r    = (uint16_t*)(ws + off); off += (size_t)H_NUM * S_LEN * D_DIM * 2;
  uint16_t* k_r    = (uint16_t*)(ws + off); off += (size_t)G_NUM * S_LEN * D_DIM * 2;
  uint16_t* v_t    = (uint16_t*)(ws + off); off += (size_t)G_NUM * D_DIM * S_LEN * 2;
  uint16_t* o_r    = (uint16_t*)(ws + off); off += (size_t)S_LEN * E_DIM * 2;
  // x_bf aliases o_r: consumed by gemm_qkv before attn writes o_r (stream-ordered).
  uint16_t* x_bf   = o_r;  // 4096x2048 bf16

  // edge conversions: fp32 -> bf16
  conv_f2b<<<(S_LEN * E_DIM) / (256 * 8), 256, 0, stream>>>(x, x_bf);
  transpose_f2b<<<dim3(QKV_N / 64, E_DIM / 64), 256, 0, stream>>>(w_in, w_inT, QKV_N, E_DIM);
  transpose_f2b<<<dim3(E_DIM / 64, E_DIM / 64), 256, 0, stream>>>(w_out, w_outT, E_DIM, E_DIM);
  // fused: qkv GEMM + rope + split into q_r / k_r / v_t
  gemm_qkv<<<(S_LEN / 128) * (QKV_N / 128), 256, 0, stream>>>(
      x_bf, w_inT, fcos, fsin, q_r, k_r, v_t, E_DIM, S_LEN / 128);
  // attention (QBLK=128, 4 waves x 32 rows, 32x32 MFMA)
  attn_kernel<<<dim3(S_LEN / 128, H_NUM), 256, 0, stream>>>(q_r, k_r, v_t, o_r);
  // out = o @ w_out  (fp32 out)
  gemm_bt<<<(S_LEN / 128) * (E_DIM / 128), 256, 0, stream>>>(o_r, w_outT, nullptr, out,
                                                             S_LEN, E_DIM, E_DIM, S_LEN / 128);
}

// Round 10
// 189.259 us; speedup vs baseline: 1.2254x; 1.0153x over previous
//
#include <hip/hip_runtime.h>
#include <stdint.h>

using bf16x8 = __attribute__((ext_vector_type(8))) __bf16;
using f32x4  = __attribute__((ext_vector_type(4))) float;
using f32x16 = __attribute__((ext_vector_type(16))) float;
using u16x8  = __attribute__((ext_vector_type(8))) uint16_t;
using u16x4  = __attribute__((ext_vector_type(4))) uint16_t;

#define S_LEN 4096
#define E_DIM 2048
#define D_DIM 128
#define H_NUM 16
#define G_NUM 4
#define QKV_N 3072
#define SCALE 0.08838834764831845f

__device__ inline float bf2f(uint16_t b) {
  union { uint32_t u; float f; } v; v.u = ((uint32_t)b) << 16; return v.f;
}
__device__ inline uint16_t f2bf(float f) {
  union { float f; uint32_t u; } v; v.f = f;
  uint32_t u = v.u + 0x7FFFu + ((v.u >> 16) & 1u);
  return (uint16_t)(u >> 16);
}
__device__ inline uint32_t packbf(float a, float b) {  // (lo=a, hi=b) round-half-up
  union { float f; uint32_t u; } x, y; x.f = a; y.f = b;
  return ((x.u + 0x8000u) >> 16) | ((y.u + 0x8000u) & 0xFFFF0000u);
}
__device__ inline void plswap(uint32_t& a, uint32_t& b) {
  asm volatile("v_permlane32_swap_b32 %0, %1" : "+v"(a), "+v"(b));
}
__device__ inline void gload_lds16(const void* g, void* l) {
  __builtin_amdgcn_global_load_lds((const __attribute__((address_space(1))) void*)g,
                                   (__attribute__((address_space(3))) void*)l, 16, 0, 0);
}

// ---------------- fused prep: x fp32->bf16 ; w_in^T ; w_out^T ----------------
// blocks [0,4096): conv ; [4096,5632): w_in transpose ; [5632,6656): w_out transpose
__global__ __launch_bounds__(256) void prep_all(
    const float* __restrict__ x, const float* __restrict__ w_in,
    const float* __restrict__ w_out, uint16_t* __restrict__ x_bf,
    uint16_t* __restrict__ w_inT, uint16_t* __restrict__ w_outT)
{
  const int bid = blockIdx.x;
  const int t = threadIdx.x;
  if (bid < 4096) {
    const size_t i = ((size_t)bid * 256 + t) * 8;
    float4 a = *(const float4*)(x + i);
    float4 b = *(const float4*)(x + i + 4);
    u16x8 o;
    o[0] = f2bf(a.x); o[1] = f2bf(a.y); o[2] = f2bf(a.z); o[3] = f2bf(a.w);
    o[4] = f2bf(b.x); o[5] = f2bf(b.y); o[6] = f2bf(b.z); o[7] = f2bf(b.w);
    *(u16x8*)(x_bf + i) = o;
    return;
  }
  __shared__ __align__(16) uint16_t tile[64][65];
  const float* in; uint16_t* out; int ldi, ldo, c0, r0;
  if (bid < 4096 + 1536) {
    const int r = bid - 4096;
    in = w_in; out = w_inT; ldi = QKV_N; ldo = E_DIM;
    c0 = (r % 48) * 64; r0 = (r / 48) * 64;
  } else {
    const int r = bid - 5632;
    in = w_out; out = w_outT; ldi = E_DIM; ldo = E_DIM;
    c0 = (r & 31) * 64; r0 = (r >> 5) * 64;
  }
#pragma unroll
  for (int i = 0; i < 16; ++i) {
    int idx = t + i * 256;
    int rr = idx >> 6, cc = idx & 63;
    tile[rr][cc] = f2bf(in[(size_t)(r0 + rr) * ldi + c0 + cc]);
  }
  __syncthreads();
#pragma unroll
  for (int i = 0; i < 16; ++i) {
    int idx = t + i * 256;
    int cc = idx >> 6, rr = idx & 63;
    out[(size_t)(c0 + cc) * ldo + r0 + rr] = tile[rr][cc];
  }
}

// ================= shared GEMM main-loop pieces (2-phase, swizzled) =================
#define GEMM_PROLOGUE(A_, Bt_, K_)                                                \
  const int tid = threadIdx.x, w = tid >> 6, lane = tid & 63;                     \
  const int lr = lane & 15, lq = lane >> 4;                                       \
  const int wr = w >> 1, wc = w & 1;                                              \
  f32x4 acc[4][4];                                                                \
  _Pragma("unroll") for (int i = 0; i < 4; ++i)                                   \
  _Pragma("unroll") for (int j = 0; j < 4; ++j) acc[i][j] = (f32x4){0.f,0.f,0.f,0.f}; \
  const int nk = (K_) >> 5;                                                       \
  const int colb = ((lane & 3) ^ ((lane >> 3) & 3)) << 4;                         \
  const int rbase0 = w * 32 + (lane >> 2);                                        \
  const char* gA0 = (const char*)(A_) + ((size_t)(m0 + rbase0) * (K_)) * 2 + colb;      \
  const char* gA1 = (const char*)(A_) + ((size_t)(m0 + rbase0 + 16) * (K_)) * 2 + colb; \
  const char* gB0 = (const char*)(Bt_) + ((size_t)(n0 + rbase0) * (K_)) * 2 + colb;     \
  const char* gB1 = (const char*)(Bt_) + ((size_t)(n0 + rbase0 + 16) * (K_)) * 2 + colb;\
  const int d0 = (w * 2) * 1024;                                                  \
  const int d1 = (w * 2 + 1) * 1024;                                              \
  const int sw = (lq ^ ((lr >> 1) & 3)) << 3;

#define GS(buf, kt)                                                     \
  {                                                                     \
    const size_t _ko = (size_t)(kt) * 64;                               \
    gload_lds16(gA0 + _ko, (char*)sA + (buf) * 8192 + d0);              \
    gload_lds16(gA1 + _ko, (char*)sA + (buf) * 8192 + d1);              \
    gload_lds16(gB0 + _ko, (char*)sB + (buf) * 8192 + d0);              \
    gload_lds16(gB1 + _ko, (char*)sB + (buf) * 8192 + d1);              \
  }

#define GEMM_MAINLOOP                                                            \
  GS(0, 0)                                                                       \
  for (int kt = 0; kt < nk; ++kt) {                                              \
    const int buf = kt & 1;                                                      \
    if (kt + 1 < nk) {                                                           \
      GS(buf ^ 1, kt + 1)                                                        \
      asm volatile("s_waitcnt vmcnt(4)" ::: "memory");                           \
    } else {                                                                     \
      asm volatile("s_waitcnt vmcnt(0)" ::: "memory");                           \
    }                                                                            \
    __builtin_amdgcn_s_barrier();                                                \
    asm volatile("" ::: "memory");                                               \
    const uint16_t* Ab = sA[buf];                                                \
    const uint16_t* Bb = sB[buf];                                                \
    bf16x8 af[4], bfj[4];                                                        \
    _Pragma("unroll") for (int i = 0; i < 4; ++i)                                \
      af[i] = *(const bf16x8*)(Ab + (wr * 64 + i * 16 + lr) * 32 + sw);          \
    _Pragma("unroll") for (int j = 0; j < 4; ++j)                                \
      bfj[j] = *(const bf16x8*)(Bb + (wc * 64 + j * 16 + lr) * 32 + sw);         \
    __builtin_amdgcn_s_setprio(1);                                               \
    _Pragma("unroll") for (int i = 0; i < 4; ++i)                                \
    _Pragma("unroll") for (int j = 0; j < 4; ++j)                                \
      acc[i][j] = __builtin_amdgcn_mfma_f32_16x16x32_bf16(af[i], bfj[j], acc[i][j], 0, 0, 0); \
    __builtin_amdgcn_s_setprio(0);                                               \
    __builtin_amdgcn_s_barrier();                                                \
    asm volatile("" ::: "memory");                                               \
  }

// ---------------- GEMM (generic): C = A * Bt^T, fp32 or bf16 out ----------------
__global__ __launch_bounds__(256, 4) void gemm_bt(
    const uint16_t* __restrict__ A, const uint16_t* __restrict__ Bt,
    uint16_t* __restrict__ Cb, float* __restrict__ Cf, int M, int N, int K, int nwgm)
{
  __shared__ __align__(16) uint16_t sA[2][128 * 32];
  __shared__ __align__(16) uint16_t sB[2][128 * 32];
  const int nwg = gridDim.x;
  const int id = ((int)blockIdx.x & 7) * (nwg >> 3) + ((int)blockIdx.x >> 3);
  const int m0 = (id % nwgm) * 128, n0 = (id / nwgm) * 128;
  GEMM_PROLOGUE(A, Bt, K)
  GEMM_MAINLOOP

  if (Cf) {
#pragma unroll
    for (int i = 0; i < 4; ++i)
#pragma unroll
      for (int j = 0; j < 4; ++j)
#pragma unroll
        for (int r = 0; r < 4; ++r)
          Cf[(size_t)(m0 + wr * 64 + i * 16 + lq * 4 + r) * N + n0 + wc * 64 + j * 16 + lr] =
              acc[i][j][r];
  } else {
#pragma unroll
    for (int i = 0; i < 4; ++i)
#pragma unroll
      for (int j = 0; j < 4; ++j)
#pragma unroll
        for (int r = 0; r < 4; ++r)
          Cb[(size_t)(m0 + wr * 64 + i * 16 + lq * 4 + r) * N + n0 + wc * 64 + j * 16 + lr] =
              f2bf(acc[i][j][r]);
  }
}

// ---------------- GEMM1 + fused RoPE/split epilogue ----------------
// q/k tiles: in-register rope (partner via shfl_xor(1)), coalesced store.
// v tiles: transpose via swizzled LDS (reusing sA/sB, safe after final mainloop
// barrier) -> coalesced 16B stores into v_t[g][d][s].
__global__ __launch_bounds__(256, 4) void gemm_qkv(
    const uint16_t* __restrict__ A, const uint16_t* __restrict__ Bt,
    const float* __restrict__ cosb, const float* __restrict__ sinb,
    uint16_t* __restrict__ q_r, uint16_t* __restrict__ k_r,
    uint16_t* __restrict__ v_t, int K, int nwgm)
{
  __shared__ __align__(16) uint16_t sA[2][128 * 32];
  __shared__ __align__(16) uint16_t sB[2][128 * 32];
  const int nwg = gridDim.x;
  const int id = ((int)blockIdx.x & 7) * (nwg >> 3) + ((int)blockIdx.x >> 3);
  const int m0 = (id % nwgm) * 128, n0 = (id / nwgm) * 128;
  GEMM_PROLOGUE(A, Bt, K)
  GEMM_MAINLOOP

  if (n0 < 2560) {  // q or k: rope
    const bool isq = (n0 < E_DIM);
    uint16_t* dstb = isq ? (q_r + (size_t)(n0 >> 7) * S_LEN * D_DIM)
                         : (k_r + (size_t)((n0 - E_DIM) >> 7) * S_LEN * D_DIM);
    const bool odd = (lr & 1);
#pragma unroll
    for (int i = 0; i < 4; ++i)
#pragma unroll
      for (int j = 0; j < 4; ++j) {
        const int d = wc * 64 + j * 16 + lr;
        const int dd = d >> 1;
#pragma unroll
        for (int r = 0; r < 4; ++r) {
          const int s = m0 + wr * 64 + i * 16 + lq * 4 + r;
          const float v = acc[i][j][r];
          const float p = __shfl_xor(v, 1);
          const float cf = cosb[s * 64 + dd];
          const float sf = sinb[s * 64 + dd];
          float o = odd ? (p * sf + v * cf) : (v * cf - p * sf);
          if (isq) o *= SCALE;
          dstb[(size_t)s * D_DIM + d] = f2bf(o);
        }
      }
  } else {  // v: LDS transpose then coalesced store
    // wc=0 waves (d 0..63) -> sA region; wc=1 waves (d 64..127) -> sB region.
    // layout: vT[dl][s ^ ((dl&15)<<3)], dl = d&63.  b64 writes, b128 reads.
    uint16_t* vTb = wc ? (uint16_t*)sB : (uint16_t*)sA;  // 64*128 elems = 16 KB
#pragma unroll
    for (int i = 0; i < 4; ++i)
#pragma unroll
      for (int j = 0; j < 4; ++j) {
        const int dl = j * 16 + lr;
        const int s0 = wr * 64 + i * 16 + lq * 4;
        u16x4 pv;
        pv[0] = f2bf(acc[i][j][0]); pv[1] = f2bf(acc[i][j][1]);
        pv[2] = f2bf(acc[i][j][2]); pv[3] = f2bf(acc[i][j][3]);
        *(u16x4*)(vTb + dl * 128 + (s0 ^ ((dl & 15) << 3))) = pv;
      }
    __syncthreads();
    uint16_t* dstv = v_t + (size_t)((n0 - 2560) >> 7) * D_DIM * S_LEN;
    const uint16_t* src = (tid < 128) ? (const uint16_t*)sA : (const uint16_t*)sB;
    const int dl = (tid & 127) >> 1;
    const int dg = (tid >> 7) * 64 + dl;
    const int sc0 = (tid & 1) * 64;
#pragma unroll
    for (int k8 = 0; k8 < 8; ++k8) {
      const int sc = sc0 + k8 * 8;
      u16x8 v = *(const u16x8*)(src + dl * 128 + (sc ^ ((dl & 15) << 3)));
      *(u16x8*)(dstv + (size_t)dg * S_LEN + m0 + sc) = v;
    }
  }
}

// ---------------- flash attention, window [p-1024, p] ----------------
__global__ __launch_bounds__(256, 2) void attn_kernel(
    const uint16_t* __restrict__ q_r, const uint16_t* __restrict__ k_r,
    const uint16_t* __restrict__ v_t, uint16_t* __restrict__ o_r)
{
  __shared__ __align__(16) uint16_t sK[2][64 * 128];   // [key][d], swizzled
  __shared__ __align__(16) uint16_t sVT[2][128 * 64];  // [d][key], swizzled
  const int h = blockIdx.y, g = h >> 2;
  const int q0 = blockIdx.x * 128;
  const int tid = threadIdx.x, w = tid >> 6, lane = tid & 63;
  const int lc = lane & 31, hi = lane >> 5;
  const int pmin = q0 + w * 32, pmax = pmin + 31;
  const int pq = pmin + lc;

  bf16x8 aq[8];
  {
    const uint16_t* qb = q_r + ((size_t)h * S_LEN + pq) * D_DIM + hi * 8;
#pragma unroll
    for (int ks = 0; ks < 8; ++ks) aq[ks] = *(const bf16x8*)(qb + ks * 16);
  }
  f32x16 accO[4];
#pragma unroll
  for (int dt = 0; dt < 4; ++dt) accO[dt] = 0;
  float M = -1e30f, L = 0.f;

  const int jstart = (q0 >= 1024) ? (q0 - 1024) : 0;
  const int nt = (q0 + 128 - jstart) >> 6;
  const char* kb = (const char*)(k_r + ((size_t)g * S_LEN + jstart) * D_DIM);
  const char* vb = (const char*)(v_t + (size_t)g * D_DIM * S_LEN + jstart);

  const int kc_row = lane >> 4;
  const int k_col0 = (lane & 15) << 4;
  const int v_scol = (((lane & 7) ^ (lane >> 3)) << 4);
  const int v_row = lane >> 3;

#define STAGE_KV(buf, tt)                                                              \
  {                                                                                    \
    const char* kt_ = kb + (size_t)(tt) * 16384;                                       \
    const char* vt_ = vb + (size_t)(tt) * 128;                                         \
    _Pragma("unroll")                                                                  \
    for (int it = 0; it < 4; ++it) {                                                   \
      const int c = w * 4 + it;                                                        \
      const int krow = c * 4 + kc_row;                                                 \
      const int kscol = k_col0 ^ ((krow & 7) << 4);                                    \
      gload_lds16(kt_ + krow * 256 + kscol, (char*)sK[buf] + c * 1024 + lane * 16);    \
      const int vrow = c * 8 + v_row;                                                  \
      gload_lds16(vt_ + (size_t)vrow * (S_LEN * 2) + v_scol,                           \
                  (char*)sVT[buf] + c * 1024 + lane * 16);                             \
    }                                                                                  \
  }

  STAGE_KV(0, 0)
  asm volatile("s_waitcnt vmcnt(0)" ::: "memory");
  __syncthreads();

  for (int t = 0; t < nt; ++t) {
    const int b = t & 1;
    if (t + 1 < nt) STAGE_KV(b ^ 1, t + 1)
    const int j0 = jstart + t * 64;
    const uint16_t* Kb = sK[b];
    const uint16_t* Vb = sVT[b];

    const bool active = (j0 <= pmax) && (j0 + 63 + 1024 >= pmin);
    if (active) {
      f32x16 accS[2];
      accS[0] = 0; accS[1] = 0;
      __builtin_amdgcn_s_setprio(1);
#pragma unroll
      for (int rt = 0; rt < 2; ++rt) {
        const int krow = rt * 32 + lc;
        const int ksw = (krow & 7) << 3;
#pragma unroll
        for (int ks = 0; ks < 8; ++ks) {
          bf16x8 ak = *(const bf16x8*)(Kb + krow * 128 + ((ks * 16 + hi * 8) ^ ksw));
          accS[rt] = __builtin_amdgcn_mfma_f32_32x32x16_bf16(ak, aq[ks], accS[rt], 0, 0, 0);
        }
      }
      __builtin_amdgcn_s_setprio(0);

      const bool need_mask = (j0 + 63 > pmin) || (j0 < pmax - 1024);
      if (need_mask) {
#pragma unroll
        for (int rt = 0; rt < 2; ++rt)
#pragma unroll
          for (int c = 0; c < 16; ++c) {
            const int j = j0 + rt * 32 + (c & 3) + 8 * (c >> 2) + 4 * hi;
            const bool ok = (j <= pq) && (j + 1024 >= pq);
            accS[rt][c] = ok ? accS[rt][c] : -1e30f;
          }
      }

      float mx = accS[0][0];
#pragma unroll
      for (int rt = 0; rt < 2; ++rt)
#pragma unroll
        for (int c = 0; c < 16; ++c) mx = fmaxf(mx, accS[rt][c]);
      mx = fmaxf(mx, __shfl_xor(mx, 32));

      if (__any(mx > M + 4.f)) {
        const float Mn = fmaxf(M, mx);
        const float al = __expf(M - Mn);
        M = Mn;
        L *= al;
        float alr[16];
#pragma unroll
        for (int c = 0; c < 16; ++c) alr[c] = __shfl(al, (c & 3) + 8 * (c >> 2) + 4 * hi);
#pragma unroll
        for (int dt = 0; dt < 4; ++dt)
#pragma unroll
          for (int c = 0; c < 16; ++c) accO[dt][c] *= alr[c];
      }

      float rs = 0.f;
#pragma unroll
      for (int rt = 0; rt < 2; ++rt)
#pragma unroll
        for (int c = 0; c < 16; ++c) {
          const float pv = __expf(accS[rt][c] - M);
          accS[rt][c] = pv;
          rs += pv;
        }
      rs += __shfl_xor(rs, 32);
      L += rs;

      __builtin_amdgcn_s_setprio(1);
#pragma unroll
      for (int rt = 0; rt < 2; ++rt) {
        uint32_t wv[8];
#pragma unroll
        for (int jj = 0; jj < 8; ++jj)
          wv[jj] = packbf(accS[rt][2 * jj], accS[rt][2 * jj + 1]);
        plswap(wv[0], wv[2]); plswap(wv[1], wv[3]);
        plswap(wv[4], wv[6]); plswap(wv[5], wv[7]);
#pragma unroll
        for (int sub = 0; sub < 2; ++sub) {
          union { uint32_t u[4]; bf16x8 v; } ap;
          ap.u[0] = wv[sub * 4 + 0]; ap.u[1] = wv[sub * 4 + 1];
          ap.u[2] = wv[sub * 4 + 2]; ap.u[3] = wv[sub * 4 + 3];
          const int kbase = rt * 32 + sub * 16 + hi * 8;
#pragma unroll
          for (int dt = 0; dt < 4; ++dt) {
            const int vrow = dt * 32 + lc;
            bf16x8 bv = *(const bf16x8*)(Vb + vrow * 64 + (kbase ^ ((vrow & 7) << 3)));
            accO[dt] = __builtin_amdgcn_mfma_f32_32x32x16_bf16(ap.v, bv, accO[dt], 0, 0, 0);
          }
        }
      }
      __builtin_amdgcn_s_setprio(0);
    }

    asm volatile("s_waitcnt vmcnt(0)" ::: "memory");
    __syncthreads();
  }

  const float ivl = 1.f / L;
  float il[16];
#pragma unroll
  for (int c = 0; c < 16; ++c) il[c] = __shfl(ivl, (c & 3) + 8 * (c >> 2) + 4 * hi);
#pragma unroll
  for (int dt = 0; dt < 4; ++dt)
#pragma unroll
    for (int c = 0; c < 16; ++c) {
      const int p = pmin + (c & 3) + 8 * (c >> 2) + 4 * hi;
      o_r[(size_t)p * E_DIM + h * D_DIM + dt * 32 + lc] = f2bf(accO[dt][c] * il[c]);
    }
}

extern "C" void kernel_launch(void* const* d_in, const int* in_sizes, int n_in,
                              void* d_out, int out_size, void* d_ws, size_t ws_size,
                              hipStream_t stream) {
  const float* x     = (const float*)d_in[0];
  const float* fcos  = (const float*)d_in[1];
  const float* fsin  = (const float*)d_in[2];
  const float* w_in  = (const float*)d_in[3];
  const float* w_out = (const float*)d_in[4];
  float* out = (float*)d_out;

  char* ws = (char*)d_ws;
  size_t off = 0;
  uint16_t* w_inT  = (uint16_t*)(ws + off); off += (size_t)QKV_N * E_DIM * 2;
  uint16_t* w_outT = (uint16_t*)(ws + off); off += (size_t)E_DIM * E_DIM * 2;
  uint16_t* q_r    = (uint16_t*)(ws + off); off += (size_t)H_NUM * S_LEN * D_DIM * 2;
  uint16_t* k_r    = (uint16_t*)(ws + off); off += (size_t)G_NUM * S_LEN * D_DIM * 2;
  uint16_t* v_t    = (uint16_t*)(ws + off); off += (size_t)G_NUM * D_DIM * S_LEN * 2;
  uint16_t* o_r    = (uint16_t*)(ws + off); off += (size_t)S_LEN * E_DIM * 2;
  // x_bf aliases o_r: consumed by gemm_qkv before attn writes o_r (stream-ordered).
  uint16_t* x_bf   = o_r;

  // fused prep (conv + both weight transposes)
  prep_all<<<4096 + 1536 + 1024, 256, 0, stream>>>(x, w_in, w_out, x_bf, w_inT, w_outT);
  // fused: qkv GEMM + rope + split into q_r / k_r / v_t
  gemm_qkv<<<(S_LEN / 128) * (QKV_N / 128), 256, 0, stream>>>(
      x_bf, w_inT, fcos, fsin, q_r, k_r, v_t, E_DIM, S_LEN / 128);
  // attention (QBLK=128, 4 waves x 32 rows, 32x32 MFMA)
  attn_kernel<<<dim3(S_LEN / 128, H_NUM), 256, 0, stream>>>(q_r, k_r, v_t, o_r);
  // out = o @ w_out  (fp32 out)
  gemm_bt<<<(S_LEN / 128) * (E_DIM / 128), 256, 0, stream>>>(o_r, w_outT, nullptr, out,
                                                             S_LEN, E_DIM, E_DIM, S_LEN / 128);
}

// Round 11
// 185.307 us; speedup vs baseline: 1.2516x; 1.0213x over previous
//
#include <hip/hip_runtime.h>
#include <stdint.h>

using bf16x8 = __attribute__((ext_vector_type(8))) __bf16;
using f32x4  = __attribute__((ext_vector_type(4))) float;
using f32x16 = __attribute__((ext_vector_type(16))) float;
using u16x8  = __attribute__((ext_vector_type(8))) uint16_t;
using u16x4  = __attribute__((ext_vector_type(4))) uint16_t;

#define S_LEN 4096
#define E_DIM 2048
#define D_DIM 128
#define H_NUM 16
#define G_NUM 4
#define QKV_N 3072
#define SCALE 0.08838834764831845f

__device__ inline float bf2f(uint16_t b) {
  union { uint32_t u; float f; } v; v.u = ((uint32_t)b) << 16; return v.f;
}
__device__ inline uint16_t f2bf(float f) {
  union { float f; uint32_t u; } v; v.f = f;
  uint32_t u = v.u + 0x7FFFu + ((v.u >> 16) & 1u);
  return (uint16_t)(u >> 16);
}
__device__ inline uint32_t packbf(float a, float b) {
  union { float f; uint32_t u; } x, y; x.f = a; y.f = b;
  return ((x.u + 0x8000u) >> 16) | ((y.u + 0x8000u) & 0xFFFF0000u);
}
__device__ inline void plswap(uint32_t& a, uint32_t& b) {
  asm volatile("v_permlane32_swap_b32 %0, %1" : "+v"(a), "+v"(b));
}
__device__ inline void gload_lds16(const void* g, void* l) {
  __builtin_amdgcn_global_load_lds((const __attribute__((address_space(1))) void*)g,
                                   (__attribute__((address_space(3))) void*)l, 16, 0, 0);
}

// ---------------- fused prep: x fp32->bf16 ; w_in^T ; w_out^T ----------------
__global__ __launch_bounds__(256) void prep_all(
    const float* __restrict__ x, const float* __restrict__ w_in,
    const float* __restrict__ w_out, uint16_t* __restrict__ x_bf,
    uint16_t* __restrict__ w_inT, uint16_t* __restrict__ w_outT)
{
  const int bid = blockIdx.x;
  const int t = threadIdx.x;
  if (bid < 4096) {
    const size_t i = ((size_t)bid * 256 + t) * 8;
    float4 a = *(const float4*)(x + i);
    float4 b = *(const float4*)(x + i + 4);
    u16x8 o;
    o[0] = f2bf(a.x); o[1] = f2bf(a.y); o[2] = f2bf(a.z); o[3] = f2bf(a.w);
    o[4] = f2bf(b.x); o[5] = f2bf(b.y); o[6] = f2bf(b.z); o[7] = f2bf(b.w);
    *(u16x8*)(x_bf + i) = o;
    return;
  }
  __shared__ __align__(16) uint16_t tile[64][65];
  const float* in; uint16_t* out; int ldi, ldo, c0, r0;
  if (bid < 4096 + 1536) {
    const int r = bid - 4096;
    in = w_in; out = w_inT; ldi = QKV_N; ldo = E_DIM;
    c0 = (r % 48) * 64; r0 = (r / 48) * 64;
  } else {
    const int r = bid - 5632;
    in = w_out; out = w_outT; ldi = E_DIM; ldo = E_DIM;
    c0 = (r & 31) * 64; r0 = (r >> 5) * 64;
  }
#pragma unroll
  for (int i = 0; i < 16; ++i) {
    int idx = t + i * 256;
    int rr = idx >> 6, cc = idx & 63;
    tile[rr][cc] = f2bf(in[(size_t)(r0 + rr) * ldi + c0 + cc]);
  }
  __syncthreads();
#pragma unroll
  for (int i = 0; i < 16; ++i) {
    int idx = t + i * 256;
    int cc = idx >> 6, rr = idx & 63;
    out[(size_t)(c0 + cc) * ldo + r0 + rr] = tile[rr][cc];
  }
}

// ================= 2-phase GEMM (for gemm2) =================
#define GEMM_PROLOGUE(A_, Bt_, K_)                                                \
  const int tid = threadIdx.x, w = tid >> 6, lane = tid & 63;                     \
  const int lr = lane & 15, lq = lane >> 4;                                       \
  const int wr = w >> 1, wc = w & 1;                                              \
  f32x4 acc[4][4];                                                                \
  _Pragma("unroll") for (int i = 0; i < 4; ++i)                                   \
  _Pragma("unroll") for (int j = 0; j < 4; ++j) acc[i][j] = (f32x4){0.f,0.f,0.f,0.f}; \
  const int nk = (K_) >> 5;                                                       \
  const int colb = ((lane & 3) ^ ((lane >> 3) & 3)) << 4;                         \
  const int rbase0 = w * 32 + (lane >> 2);                                        \
  const char* gA0 = (const char*)(A_) + ((size_t)(m0 + rbase0) * (K_)) * 2 + colb;      \
  const char* gA1 = (const char*)(A_) + ((size_t)(m0 + rbase0 + 16) * (K_)) * 2 + colb; \
  const char* gB0 = (const char*)(Bt_) + ((size_t)(n0 + rbase0) * (K_)) * 2 + colb;     \
  const char* gB1 = (const char*)(Bt_) + ((size_t)(n0 + rbase0 + 16) * (K_)) * 2 + colb;\
  const int d0 = (w * 2) * 1024;                                                  \
  const int d1 = (w * 2 + 1) * 1024;                                              \
  const int sw = (lq ^ ((lr >> 1) & 3)) << 3;

#define GS(buf, kt)                                                     \
  {                                                                     \
    const size_t _ko = (size_t)(kt) * 64;                               \
    gload_lds16(gA0 + _ko, (char*)sA + (buf) * 8192 + d0);              \
    gload_lds16(gA1 + _ko, (char*)sA + (buf) * 8192 + d1);              \
    gload_lds16(gB0 + _ko, (char*)sB + (buf) * 8192 + d0);              \
    gload_lds16(gB1 + _ko, (char*)sB + (buf) * 8192 + d1);              \
  }

#define GEMM_MAINLOOP                                                            \
  GS(0, 0)                                                                       \
  for (int kt = 0; kt < nk; ++kt) {                                              \
    const int buf = kt & 1;                                                      \
    if (kt + 1 < nk) {                                                           \
      GS(buf ^ 1, kt + 1)                                                        \
      asm volatile("s_waitcnt vmcnt(4)" ::: "memory");                           \
    } else {                                                                     \
      asm volatile("s_waitcnt vmcnt(0)" ::: "memory");                           \
    }                                                                            \
    __builtin_amdgcn_s_barrier();                                                \
    asm volatile("" ::: "memory");                                               \
    const uint16_t* Ab = sA[buf];                                                \
    const uint16_t* Bb = sB[buf];                                                \
    bf16x8 af[4], bfj[4];                                                        \
    _Pragma("unroll") for (int i = 0; i < 4; ++i)                                \
      af[i] = *(const bf16x8*)(Ab + (wr * 64 + i * 16 + lr) * 32 + sw);          \
    _Pragma("unroll") for (int j = 0; j < 4; ++j)                                \
      bfj[j] = *(const bf16x8*)(Bb + (wc * 64 + j * 16 + lr) * 32 + sw);         \
    __builtin_amdgcn_s_setprio(1);                                               \
    _Pragma("unroll") for (int i = 0; i < 4; ++i)                                \
    _Pragma("unroll") for (int j = 0; j < 4; ++j)                                \
      acc[i][j] = __builtin_amdgcn_mfma_f32_16x16x32_bf16(af[i], bfj[j], acc[i][j], 0, 0, 0); \
    __builtin_amdgcn_s_setprio(0);                                               \
    __builtin_amdgcn_s_barrier();                                                \
    asm volatile("" ::: "memory");                                               \
  }

__global__ __launch_bounds__(256, 4) void gemm_bt(
    const uint16_t* __restrict__ A, const uint16_t* __restrict__ Bt,
    uint16_t* __restrict__ Cb, float* __restrict__ Cf, int M, int N, int K, int nwgm)
{
  __shared__ __align__(16) uint16_t sA[2][128 * 32];
  __shared__ __align__(16) uint16_t sB[2][128 * 32];
  const int nwg = gridDim.x;
  const int id = ((int)blockIdx.x & 7) * (nwg >> 3) + ((int)blockIdx.x >> 3);
  const int m0 = (id % nwgm) * 128, n0 = (id / nwgm) * 128;
  GEMM_PROLOGUE(A, Bt, K)
  GEMM_MAINLOOP

  if (Cf) {
#pragma unroll
    for (int i = 0; i < 4; ++i)
#pragma unroll
      for (int j = 0; j < 4; ++j)
#pragma unroll
        for (int r = 0; r < 4; ++r)
          Cf[(size_t)(m0 + wr * 64 + i * 16 + lq * 4 + r) * N + n0 + wc * 64 + j * 16 + lr] =
              acc[i][j][r];
  } else {
#pragma unroll
    for (int i = 0; i < 4; ++i)
#pragma unroll
      for (int j = 0; j < 4; ++j)
#pragma unroll
        for (int r = 0; r < 4; ++r)
          Cb[(size_t)(m0 + wr * 64 + i * 16 + lq * 4 + r) * N + n0 + wc * 64 + j * 16 + lr] =
              f2bf(acc[i][j][r]);
  }
}

// ================= 8-phase 256x256 GEMM1 + fused RoPE/split =================
// BK=64, 8 waves (2M x 4N), 128 KB LDS (2 dbuf x {Ah0,Ah1,Bh0,Bh1} x 16 KB).
// Per tile t (buf b): 4 phases {ds_read frags || stage 1 half -> barrier ->
// 16 MFMA (setprio) -> barrier}. Stage ledger (region-safe, derived):
//   ph1: A-h0(t+1)->buf^1   (A(buf^1) free since t-1 done)
//   ph2: A-h1(t+1)->buf^1
//   ph3: B-h0(t+2)->buf     (B(buf) fully read in ph1, held in regs)
//   ph4: B-h1(t+2)->buf ; vmcnt(4) => t+1's A+B landed (only 2 B(t+2) halves
//        may remain outstanding). Tail boundaries use vmcnt(0).
// Swizzle both-sides: granule (ks*4+lq)^(lr&7); staged via global chunk
// (tid&7)^(srow&7) with linear LDS dest (rule #21).
__global__ __launch_bounds__(512, 2) void gemm8_qkv(
    const uint16_t* __restrict__ A, const uint16_t* __restrict__ Bt,
    const float* __restrict__ cosb, const float* __restrict__ sinb,
    uint16_t* __restrict__ q_r, uint16_t* __restrict__ k_r,
    uint16_t* __restrict__ v_t, int K, int nwgm)
{
  __shared__ __align__(16) uint16_t lds8[8][8192];  // [buf*4 + op*2 + h], 16 KB each
  const int nwg = gridDim.x;
  const int id = ((int)blockIdx.x & 7) * (nwg >> 3) + ((int)blockIdx.x >> 3);
  const int m0 = (id % nwgm) * 256, n0 = (id / nwgm) * 256;
  const int tid = threadIdx.x, w = tid >> 6, lane = tid & 63;
  const int lr = lane & 15, lq = lane >> 4;
  const int wr = w >> 2, wc = w & 3;

  f32x4 acc[8][4];
#pragma unroll
  for (int i = 0; i < 8; ++i)
#pragma unroll
    for (int j = 0; j < 4; ++j) acc[i][j] = (f32x4){0.f, 0.f, 0.f, 0.f};

  const int srow = tid >> 3;                      // 0..63
  const int schunk = (tid & 7) ^ (srow & 7);      // pre-swizzled global 16B chunk
  const size_t K2 = (size_t)K * 2;
  const char* gAb = (const char*)A + (size_t)(m0 + srow) * K2 + schunk * 16;
  const char* gBb = (const char*)Bt + (size_t)(n0 + srow) * K2 + schunk * 16;

#define ST8(op, buf, h, kt)                                                        \
  {                                                                                \
    const char* _g = ((op) ? gBb : gAb) + (size_t)(h) * 128 * K2 + (size_t)(kt) * 128; \
    char* _l = (char*)lds8[(buf) * 4 + (op) * 2 + (h)] + tid * 16;                 \
    gload_lds16(_g, _l);                                                           \
    gload_lds16(_g + 64 * K2, _l + 8192);                                          \
  }

  const int nk = K >> 6;  // BK=64
  // prologue: tile0 A+B, tile1 B; vmcnt(4) -> tile0 resident
  ST8(0, 0, 0, 0) ST8(0, 0, 1, 0) ST8(1, 0, 0, 0) ST8(1, 0, 1, 0)
  ST8(1, 1, 0, 1) ST8(1, 1, 1, 1)
  asm volatile("s_waitcnt vmcnt(4)" ::: "memory");
  __builtin_amdgcn_s_barrier();
  asm volatile("" ::: "memory");

  const int aswz0 = (lq ^ (lr & 7)) << 3;        // ks=0 granule elem offset
  const int aswz1 = ((4 + lq) ^ (lr & 7)) << 3;  // ks=1

#define PH8(afbase, SWZ, BFARR, STMT, WAIT)                                         \
  {                                                                                 \
    bf16x8 af[4];                                                                   \
    _Pragma("unroll") for (int mf = 0; mf < 4; ++mf)                                \
      af[mf] = *(const bf16x8*)(Ah + ((afbase) + mf) * 1024 + lr * 64 + (SWZ));     \
    STMT;                                                                           \
    WAIT;                                                                           \
    __builtin_amdgcn_s_barrier();                                                   \
    asm volatile("" ::: "memory");                                                  \
    __builtin_amdgcn_s_setprio(1);                                                  \
    _Pragma("unroll") for (int mf = 0; mf < 4; ++mf)                                \
    _Pragma("unroll") for (int nf = 0; nf < 4; ++nf)                                \
      acc[(afbase) + mf][nf] =                                                      \
          __builtin_amdgcn_mfma_f32_16x16x32_bf16(af[mf], BFARR[nf], acc[(afbase) + mf][nf], 0, 0, 0); \
    __builtin_amdgcn_s_setprio(0);                                                  \
    __builtin_amdgcn_s_barrier();                                                   \
    asm volatile("" ::: "memory");                                                  \
  }

  for (int t = 0; t < nk; ++t) {
    const int b = t & 1;
    const uint16_t* Ah = lds8[b * 4 + wr];              // wave's A half
    const uint16_t* Bh = lds8[b * 4 + 2 + (wc >> 1)];   // wave's B half
    const int brow = ((wc & 1) * 64 + lr) * 64;

    bf16x8 bf0[4], bf1[4];  // B frags, both k-slices, held across phases
#pragma unroll
    for (int nf = 0; nf < 4; ++nf) {
      bf0[nf] = *(const bf16x8*)(Bh + brow + nf * 1024 + aswz0);
      bf1[nf] = *(const bf16x8*)(Bh + brow + nf * 1024 + aswz1);
    }

    PH8(0, aswz0, bf0, if (t + 1 < nk) ST8(0, b ^ 1, 0, t + 1), )
    PH8(4, aswz0, bf0, if (t + 1 < nk) ST8(0, b ^ 1, 1, t + 1), )
    PH8(0, aswz1, bf1, if (t + 2 < nk) ST8(1, b, 0, t + 2), )
    PH8(4, aswz1, bf1, if (t + 2 < nk) ST8(1, b, 1, t + 2),
        if (t + 2 < nk) { asm volatile("s_waitcnt vmcnt(4)" ::: "memory"); }
        else { asm volatile("s_waitcnt vmcnt(0)" ::: "memory"); })
  }
#undef PH8
#undef ST8

  // ---- epilogue: rope (q/k) or LDS-transpose store (v) ----
  if (n0 < 2560) {
    const bool isq = (n0 < E_DIM);
    const bool odd = lr & 1;
#pragma unroll
    for (int mf = 0; mf < 8; ++mf)
#pragma unroll
      for (int nf = 0; nf < 4; ++nf) {
        const int ncol = n0 + wc * 64 + nf * 16 + lr;
        const int d = ncol & 127;
        const int dd = d >> 1;
        uint16_t* dstb = isq ? (q_r + (size_t)(ncol >> 7) * S_LEN * D_DIM)
                             : (k_r + (size_t)((ncol >> 7) - 16) * S_LEN * D_DIM);
#pragma unroll
        for (int r = 0; r < 4; ++r) {
          const int s = m0 + wr * 128 + mf * 16 + lq * 4 + r;
          const float v = acc[mf][nf][r];
          const float p = __shfl_xor(v, 1);
          const float cf = cosb[s * 64 + dd];
          const float sf = sinb[s * 64 + dd];
          float o = odd ? (p * sf + v * cf) : (v * cf - p * sf);
          if (isq) o *= SCALE;
          dstb[(size_t)s * D_DIM + d] = f2bf(o);
        }
      }
  } else {
    // v: per-wave transpose in own 16 KB LDS region (all reads done at final barrier)
    uint16_t* vT = lds8[w];  // [64 d][128 s], swizzled
#pragma unroll
    for (int mf = 0; mf < 8; ++mf)
#pragma unroll
      for (int nf = 0; nf < 4; ++nf) {
        const int dl = nf * 16 + lr;
        const int s0 = mf * 16 + lq * 4;
        u16x4 pv;
        pv[0] = f2bf(acc[mf][nf][0]); pv[1] = f2bf(acc[mf][nf][1]);
        pv[2] = f2bf(acc[mf][nf][2]); pv[3] = f2bf(acc[mf][nf][3]);
        *(u16x4*)(vT + dl * 128 + (s0 ^ ((dl & 15) << 3))) = pv;
      }
    const int vg = ((n0 - 2560) + wc * 64) >> 7;
    uint16_t* dstv = v_t + ((size_t)vg * D_DIM + (wc & 1) * 64) * S_LEN;
#pragma unroll
    for (int it = 0; it < 16; ++it) {
      const int dl = it * 4 + lq;
      const int sc = lr * 8;
      u16x8 vv = *(const u16x8*)(vT + dl * 128 + (sc ^ ((dl & 15) << 3)));
      *(u16x8*)(dstv + (size_t)dl * S_LEN + m0 + wr * 128 + sc) = vv;
    }
  }
}

// ---------------- flash attention, window [p-1024, p] ----------------
__global__ __launch_bounds__(256, 2) void attn_kernel(
    const uint16_t* __restrict__ q_r, const uint16_t* __restrict__ k_r,
    const uint16_t* __restrict__ v_t, uint16_t* __restrict__ o_r)
{
  __shared__ __align__(16) uint16_t sK[2][64 * 128];   // [key][d], swizzled
  __shared__ __align__(16) uint16_t sVT[2][128 * 64];  // [d][key], swizzled
  const int h = blockIdx.y, g = h >> 2;
  const int q0 = blockIdx.x * 128;
  const int tid = threadIdx.x, w = tid >> 6, lane = tid & 63;
  const int lc = lane & 31, hi = lane >> 5;
  const int pmin = q0 + w * 32, pmax = pmin + 31;
  const int pq = pmin + lc;

  bf16x8 aq[8];
  {
    const uint16_t* qb = q_r + ((size_t)h * S_LEN + pq) * D_DIM + hi * 8;
#pragma unroll
    for (int ks = 0; ks < 8; ++ks) aq[ks] = *(const bf16x8*)(qb + ks * 16);
  }
  f32x16 accO[4];
#pragma unroll
  for (int dt = 0; dt < 4; ++dt) accO[dt] = 0;
  float M = -1e30f, L = 0.f;

  const int jstart = (q0 >= 1024) ? (q0 - 1024) : 0;
  const int nt = (q0 + 128 - jstart) >> 6;
  const char* kb = (const char*)(k_r + ((size_t)g * S_LEN + jstart) * D_DIM);
  const char* vb = (const char*)(v_t + (size_t)g * D_DIM * S_LEN + jstart);

  const int kc_row = lane >> 4;
  const int k_col0 = (lane & 15) << 4;
  const int v_scol = (((lane & 7) ^ (lane >> 3)) << 4);
  const int v_row = lane >> 3;

#define STAGE_KV(buf, tt)                                                              \
  {                                                                                    \
    const char* kt_ = kb + (size_t)(tt) * 16384;                                       \
    const char* vt_ = vb + (size_t)(tt) * 128;                                         \
    _Pragma("unroll")                                                                  \
    for (int it = 0; it < 4; ++it) {                                                   \
      const int c = w * 4 + it;                                                        \
      const int krow = c * 4 + kc_row;                                                 \
      const int kscol = k_col0 ^ ((krow & 7) << 4);                                    \
      gload_lds16(kt_ + krow * 256 + kscol, (char*)sK[buf] + c * 1024 + lane * 16);    \
      const int vrow = c * 8 + v_row;                                                  \
      gload_lds16(vt_ + (size_t)vrow * (S_LEN * 2) + v_scol,                           \
                  (char*)sVT[buf] + c * 1024 + lane * 16);                             \
    }                                                                                  \
  }

  STAGE_KV(0, 0)
  asm volatile("s_waitcnt vmcnt(0)" ::: "memory");
  __syncthreads();

  for (int t = 0; t < nt; ++t) {
    const int b = t & 1;
    if (t + 1 < nt) STAGE_KV(b ^ 1, t + 1)
    const int j0 = jstart + t * 64;
    const uint16_t* Kb = sK[b];
    const uint16_t* Vb = sVT[b];

    const bool active = (j0 <= pmax) && (j0 + 63 + 1024 >= pmin);
    if (active) {
      f32x16 accS[2];
      accS[0] = 0; accS[1] = 0;
      __builtin_amdgcn_s_setprio(1);
#pragma unroll
      for (int rt = 0; rt < 2; ++rt) {
        const int krow = rt * 32 + lc;
        const int ksw = (krow & 7) << 3;
#pragma unroll
        for (int ks = 0; ks < 8; ++ks) {
          bf16x8 ak = *(const bf16x8*)(Kb + krow * 128 + ((ks * 16 + hi * 8) ^ ksw));
          accS[rt] = __builtin_amdgcn_mfma_f32_32x32x16_bf16(ak, aq[ks], accS[rt], 0, 0, 0);
        }
      }
      __builtin_amdgcn_s_setprio(0);

      const bool need_mask = (j0 + 63 > pmin) || (j0 < pmax - 1024);
      if (need_mask) {
#pragma unroll
        for (int rt = 0; rt < 2; ++rt)
#pragma unroll
          for (int c = 0; c < 16; ++c) {
            const int j = j0 + rt * 32 + (c & 3) + 8 * (c >> 2) + 4 * hi;
            const bool ok = (j <= pq) && (j + 1024 >= pq);
            accS[rt][c] = ok ? accS[rt][c] : -1e30f;
          }
      }

      float mx = accS[0][0];
#pragma unroll
      for (int rt = 0; rt < 2; ++rt)
#pragma unroll
        for (int c = 0; c < 16; ++c) mx = fmaxf(mx, accS[rt][c]);
      mx = fmaxf(mx, __shfl_xor(mx, 32));

      if (__any(mx > M + 4.f)) {
        const float Mn = fmaxf(M, mx);
        const float al = __expf(M - Mn);
        M = Mn;
        L *= al;
        float alr[16];
#pragma unroll
        for (int c = 0; c < 16; ++c) alr[c] = __shfl(al, (c & 3) + 8 * (c >> 2) + 4 * hi);
#pragma unroll
        for (int dt = 0; dt < 4; ++dt)
#pragma unroll
          for (int c = 0; c < 16; ++c) accO[dt][c] *= alr[c];
      }

      float rs = 0.f;
#pragma unroll
      for (int rt = 0; rt < 2; ++rt)
#pragma unroll
        for (int c = 0; c < 16; ++c) {
          const float pv = __expf(accS[rt][c] - M);
          accS[rt][c] = pv;
          rs += pv;
        }
      rs += __shfl_xor(rs, 32);
      L += rs;

      __builtin_amdgcn_s_setprio(1);
#pragma unroll
      for (int rt = 0; rt < 2; ++rt) {
        uint32_t wv[8];
#pragma unroll
        for (int jj = 0; jj < 8; ++jj)
          wv[jj] = packbf(accS[rt][2 * jj], accS[rt][2 * jj + 1]);
        plswap(wv[0], wv[2]); plswap(wv[1], wv[3]);
        plswap(wv[4], wv[6]); plswap(wv[5], wv[7]);
#pragma unroll
        for (int sub = 0; sub < 2; ++sub) {
          union { uint32_t u[4]; bf16x8 v; } ap;
          ap.u[0] = wv[sub * 4 + 0]; ap.u[1] = wv[sub * 4 + 1];
          ap.u[2] = wv[sub * 4 + 2]; ap.u[3] = wv[sub * 4 + 3];
          const int kbase = rt * 32 + sub * 16 + hi * 8;
#pragma unroll
          for (int dt = 0; dt < 4; ++dt) {
            const int vrow = dt * 32 + lc;
            bf16x8 bv = *(const bf16x8*)(Vb + vrow * 64 + (kbase ^ ((vrow & 7) << 3)));
            accO[dt] = __builtin_amdgcn_mfma_f32_32x32x16_bf16(ap.v, bv, accO[dt], 0, 0, 0);
          }
        }
      }
      __builtin_amdgcn_s_setprio(0);
    }

    asm volatile("s_waitcnt vmcnt(0)" ::: "memory");
    __syncthreads();
  }

  const float ivl = 1.f / L;
  float il[16];
#pragma unroll
  for (int c = 0; c < 16; ++c) il[c] = __shfl(ivl, (c & 3) + 8 * (c >> 2) + 4 * hi);
#pragma unroll
  for (int dt = 0; dt < 4; ++dt)
#pragma unroll
    for (int c = 0; c < 16; ++c) {
      const int p = pmin + (c & 3) + 8 * (c >> 2) + 4 * hi;
      o_r[(size_t)p * E_DIM + h * D_DIM + dt * 32 + lc] = f2bf(accO[dt][c] * il[c]);
    }
}

extern "C" void kernel_launch(void* const* d_in, const int* in_sizes, int n_in,
                              void* d_out, int out_size, void* d_ws, size_t ws_size,
                              hipStream_t stream) {
  const float* x     = (const float*)d_in[0];
  const float* fcos  = (const float*)d_in[1];
  const float* fsin  = (const float*)d_in[2];
  const float* w_in  = (const float*)d_in[3];
  const float* w_out = (const float*)d_in[4];
  float* out = (float*)d_out;

  char* ws = (char*)d_ws;
  size_t off = 0;
  uint16_t* w_inT  = (uint16_t*)(ws + off); off += (size_t)QKV_N * E_DIM * 2;
  uint16_t* w_outT = (uint16_t*)(ws + off); off += (size_t)E_DIM * E_DIM * 2;
  uint16_t* q_r    = (uint16_t*)(ws + off); off += (size_t)H_NUM * S_LEN * D_DIM * 2;
  uint16_t* k_r    = (uint16_t*)(ws + off); off += (size_t)G_NUM * S_LEN * D_DIM * 2;
  uint16_t* v_t    = (uint16_t*)(ws + off); off += (size_t)G_NUM * D_DIM * S_LEN * 2;
  uint16_t* o_r    = (uint16_t*)(ws + off); off += (size_t)S_LEN * E_DIM * 2;
  // x_bf aliases o_r: consumed by gemm8_qkv before attn writes o_r (stream-ordered).
  uint16_t* x_bf   = o_r;

  // fused prep (conv + both weight transposes)
  prep_all<<<4096 + 1536 + 1024, 256, 0, stream>>>(x, w_in, w_out, x_bf, w_inT, w_outT);
  // 8-phase 256x256 qkv GEMM + rope + split (16 M-blocks x 12 N-blocks = 192, %8==0)
  gemm8_qkv<<<(S_LEN / 256) * (QKV_N / 256), 512, 0, stream>>>(
      x_bf, w_inT, fcos, fsin, q_r, k_r, v_t, E_DIM, S_LEN / 256);
  // attention (QBLK=128, 4 waves x 32 rows, 32x32 MFMA)
  attn_kernel<<<dim3(S_LEN / 128, H_NUM), 256, 0, stream>>>(q_r, k_r, v_t, o_r);
  // out = o @ w_out  (fp32 out)
  gemm_bt<<<(S_LEN / 128) * (E_DIM / 128), 256, 0, stream>>>(o_r, w_outT, nullptr, out,
                                                             S_LEN, E_DIM, E_DIM, S_LEN / 128);
}

// Round 12
// 185.276 us; speedup vs baseline: 1.2518x; 1.0002x over previous
//
#include <hip/hip_runtime.h>
#include <stdint.h>

using bf16x8 = __attribute__((ext_vector_type(8))) __bf16;
using f32x4  = __attribute__((ext_vector_type(4))) float;
using f32x16 = __attribute__((ext_vector_type(16))) float;
using u16x8  = __attribute__((ext_vector_type(8))) uint16_t;
using u16x4  = __attribute__((ext_vector_type(4))) uint16_t;

#define S_LEN 4096
#define E_DIM 2048
#define D_DIM 128
#define H_NUM 16
#define G_NUM 4
#define QKV_N 3072
#define SCALE 0.08838834764831845f

__device__ inline float bf2f(uint16_t b) {
  union { uint32_t u; float f; } v; v.u = ((uint32_t)b) << 16; return v.f;
}
__device__ inline uint16_t f2bf(float f) {
  union { float f; uint32_t u; } v; v.f = f;
  uint32_t u = v.u + 0x7FFFu + ((v.u >> 16) & 1u);
  return (uint16_t)(u >> 16);
}
__device__ inline uint32_t packbf(float a, float b) {
  union { float f; uint32_t u; } x, y; x.f = a; y.f = b;
  return ((x.u + 0x8000u) >> 16) | ((y.u + 0x8000u) & 0xFFFF0000u);
}
__device__ inline void plswap(uint32_t& a, uint32_t& b) {
  asm volatile("v_permlane32_swap_b32 %0, %1" : "+v"(a), "+v"(b));
}
__device__ inline void gload_lds16(const void* g, void* l) {
  __builtin_amdgcn_global_load_lds((const __attribute__((address_space(1))) void*)g,
                                   (__attribute__((address_space(3))) void*)l, 16, 0, 0);
}

// ---------------- fused prep: x fp32->bf16 ; w_in^T ; w_out^T ; cs table ----------------
// blocks [0,4096): conv ; [4096,5632): w_in^T ; [5632,6656): w_out^T ;
// [6656,7680): packed float2 {cos,sin} table
__global__ __launch_bounds__(256) void prep_all(
    const float* __restrict__ x, const float* __restrict__ w_in,
    const float* __restrict__ w_out, const float* __restrict__ fcos,
    const float* __restrict__ fsin, uint16_t* __restrict__ x_bf,
    uint16_t* __restrict__ w_inT, uint16_t* __restrict__ w_outT,
    float2* __restrict__ csb)
{
  const int bid = blockIdx.x;
  const int t = threadIdx.x;
  if (bid < 4096) {
    const size_t i = ((size_t)bid * 256 + t) * 8;
    float4 a = *(const float4*)(x + i);
    float4 b = *(const float4*)(x + i + 4);
    u16x8 o;
    o[0] = f2bf(a.x); o[1] = f2bf(a.y); o[2] = f2bf(a.z); o[3] = f2bf(a.w);
    o[4] = f2bf(b.x); o[5] = f2bf(b.y); o[6] = f2bf(b.z); o[7] = f2bf(b.w);
    *(u16x8*)(x_bf + i) = o;
    return;
  }
  if (bid >= 6656) {
    const int idx = (bid - 6656) * 256 + t;  // < 4096*64
    csb[idx] = make_float2(fcos[idx], fsin[idx]);
    return;
  }
  __shared__ __align__(16) uint16_t tile[64][65];
  const float* in; uint16_t* out; int ldi, ldo, c0, r0;
  if (bid < 4096 + 1536) {
    const int r = bid - 4096;
    in = w_in; out = w_inT; ldi = QKV_N; ldo = E_DIM;
    c0 = (r % 48) * 64; r0 = (r / 48) * 64;
  } else {
    const int r = bid - 5632;
    in = w_out; out = w_outT; ldi = E_DIM; ldo = E_DIM;
    c0 = (r & 31) * 64; r0 = (r >> 5) * 64;
  }
#pragma unroll
  for (int i = 0; i < 16; ++i) {
    int idx = t + i * 256;
    int rr = idx >> 6, cc = idx & 63;
    tile[rr][cc] = f2bf(in[(size_t)(r0 + rr) * ldi + c0 + cc]);
  }
  __syncthreads();
#pragma unroll
  for (int i = 0; i < 16; ++i) {
    int idx = t + i * 256;
    int cc = idx >> 6, rr = idx & 63;
    out[(size_t)(c0 + cc) * ldo + r0 + rr] = tile[rr][cc];
  }
}

// ================= 2-phase GEMM (for gemm2) =================
#define GEMM_PROLOGUE(A_, Bt_, K_)                                                \
  const int tid = threadIdx.x, w = tid >> 6, lane = tid & 63;                     \
  const int lr = lane & 15, lq = lane >> 4;                                       \
  const int wr = w >> 1, wc = w & 1;                                              \
  f32x4 acc[4][4];                                                                \
  _Pragma("unroll") for (int i = 0; i < 4; ++i)                                   \
  _Pragma("unroll") for (int j = 0; j < 4; ++j) acc[i][j] = (f32x4){0.f,0.f,0.f,0.f}; \
  const int nk = (K_) >> 5;                                                       \
  const int colb = ((lane & 3) ^ ((lane >> 3) & 3)) << 4;                         \
  const int rbase0 = w * 32 + (lane >> 2);                                        \
  const char* gA0 = (const char*)(A_) + ((size_t)(m0 + rbase0) * (K_)) * 2 + colb;      \
  const char* gA1 = (const char*)(A_) + ((size_t)(m0 + rbase0 + 16) * (K_)) * 2 + colb; \
  const char* gB0 = (const char*)(Bt_) + ((size_t)(n0 + rbase0) * (K_)) * 2 + colb;     \
  const char* gB1 = (const char*)(Bt_) + ((size_t)(n0 + rbase0 + 16) * (K_)) * 2 + colb;\
  const int d0 = (w * 2) * 1024;                                                  \
  const int d1 = (w * 2 + 1) * 1024;                                              \
  const int sw = (lq ^ ((lr >> 1) & 3)) << 3;

#define GS(buf, kt)                                                     \
  {                                                                     \
    const size_t _ko = (size_t)(kt) * 64;                               \
    gload_lds16(gA0 + _ko, (char*)sA + (buf) * 8192 + d0);              \
    gload_lds16(gA1 + _ko, (char*)sA + (buf) * 8192 + d1);              \
    gload_lds16(gB0 + _ko, (char*)sB + (buf) * 8192 + d0);              \
    gload_lds16(gB1 + _ko, (char*)sB + (buf) * 8192 + d1);              \
  }

#define GEMM_MAINLOOP                                                            \
  GS(0, 0)                                                                       \
  for (int kt = 0; kt < nk; ++kt) {                                              \
    const int buf = kt & 1;                                                      \
    if (kt + 1 < nk) {                                                           \
      GS(buf ^ 1, kt + 1)                                                        \
      asm volatile("s_waitcnt vmcnt(4)" ::: "memory");                           \
    } else {                                                                     \
      asm volatile("s_waitcnt vmcnt(0)" ::: "memory");                           \
    }                                                                            \
    __builtin_amdgcn_s_barrier();                                                \
    asm volatile("" ::: "memory");                                               \
    const uint16_t* Ab = sA[buf];                                                \
    const uint16_t* Bb = sB[buf];                                                \
    bf16x8 af[4], bfj[4];                                                        \
    _Pragma("unroll") for (int i = 0; i < 4; ++i)                                \
      af[i] = *(const bf16x8*)(Ab + (wr * 64 + i * 16 + lr) * 32 + sw);          \
    _Pragma("unroll") for (int j = 0; j < 4; ++j)                                \
      bfj[j] = *(const bf16x8*)(Bb + (wc * 64 + j * 16 + lr) * 32 + sw);         \
    __builtin_amdgcn_s_setprio(1);                                               \
    _Pragma("unroll") for (int i = 0; i < 4; ++i)                                \
    _Pragma("unroll") for (int j = 0; j < 4; ++j)                                \
      acc[i][j] = __builtin_amdgcn_mfma_f32_16x16x32_bf16(af[i], bfj[j], acc[i][j], 0, 0, 0); \
    __builtin_amdgcn_s_setprio(0);                                               \
    __builtin_amdgcn_s_barrier();                                                \
    asm volatile("" ::: "memory");                                               \
  }

__global__ __launch_bounds__(256, 4) void gemm_bt(
    const uint16_t* __restrict__ A, const uint16_t* __restrict__ Bt,
    uint16_t* __restrict__ Cb, float* __restrict__ Cf, int M, int N, int K, int nwgm)
{
  __shared__ __align__(16) uint16_t sA[2][128 * 32];
  __shared__ __align__(16) uint16_t sB[2][128 * 32];
  const int nwg = gridDim.x;
  const int id = ((int)blockIdx.x & 7) * (nwg >> 3) + ((int)blockIdx.x >> 3);
  const int m0 = (id % nwgm) * 128, n0 = (id / nwgm) * 128;
  GEMM_PROLOGUE(A, Bt, K)
  GEMM_MAINLOOP

  if (Cf) {
#pragma unroll
    for (int i = 0; i < 4; ++i)
#pragma unroll
      for (int j = 0; j < 4; ++j)
#pragma unroll
        for (int r = 0; r < 4; ++r)
          Cf[(size_t)(m0 + wr * 64 + i * 16 + lq * 4 + r) * N + n0 + wc * 64 + j * 16 + lr] =
              acc[i][j][r];
  } else {
#pragma unroll
    for (int i = 0; i < 4; ++i)
#pragma unroll
      for (int j = 0; j < 4; ++j)
#pragma unroll
        for (int r = 0; r < 4; ++r)
          Cb[(size_t)(m0 + wr * 64 + i * 16 + lq * 4 + r) * N + n0 + wc * 64 + j * 16 + lr] =
              f2bf(acc[i][j][r]);
  }
}

// ================= 8-phase 256x256 GEMM1 + fused RoPE/split =================
__global__ __launch_bounds__(512, 2) void gemm8_qkv(
    const uint16_t* __restrict__ A, const uint16_t* __restrict__ Bt,
    const float2* __restrict__ csb,
    uint16_t* __restrict__ q_r, uint16_t* __restrict__ k_r,
    uint16_t* __restrict__ v_t, int K, int nwgm)
{
  __shared__ __align__(16) uint16_t lds8[8][8192];  // [buf*4 + op*2 + h], 16 KB each
  const int nwg = gridDim.x;
  const int id = ((int)blockIdx.x & 7) * (nwg >> 3) + ((int)blockIdx.x >> 3);
  const int m0 = (id % nwgm) * 256, n0 = (id / nwgm) * 256;
  const int tid = threadIdx.x, w = tid >> 6, lane = tid & 63;
  const int lr = lane & 15, lq = lane >> 4;
  const int wr = w >> 2, wc = w & 3;

  f32x4 acc[8][4];
#pragma unroll
  for (int i = 0; i < 8; ++i)
#pragma unroll
    for (int j = 0; j < 4; ++j) acc[i][j] = (f32x4){0.f, 0.f, 0.f, 0.f};

  const int srow = tid >> 3;
  const int schunk = (tid & 7) ^ (srow & 7);
  const size_t K2 = (size_t)K * 2;
  const char* gAb = (const char*)A + (size_t)(m0 + srow) * K2 + schunk * 16;
  const char* gBb = (const char*)Bt + (size_t)(n0 + srow) * K2 + schunk * 16;

#define ST8(op, buf, h, kt)                                                        \
  {                                                                                \
    const char* _g = ((op) ? gBb : gAb) + (size_t)(h) * 128 * K2 + (size_t)(kt) * 128; \
    char* _l = (char*)lds8[(buf) * 4 + (op) * 2 + (h)] + tid * 16;                 \
    gload_lds16(_g, _l);                                                           \
    gload_lds16(_g + 64 * K2, _l + 8192);                                          \
  }

  const int nk = K >> 6;  // BK=64
  ST8(0, 0, 0, 0) ST8(0, 0, 1, 0) ST8(1, 0, 0, 0) ST8(1, 0, 1, 0)
  ST8(1, 1, 0, 1) ST8(1, 1, 1, 1)
  asm volatile("s_waitcnt vmcnt(4)" ::: "memory");
  __builtin_amdgcn_s_barrier();
  asm volatile("" ::: "memory");

  const int aswz0 = (lq ^ (lr & 7)) << 3;
  const int aswz1 = ((4 + lq) ^ (lr & 7)) << 3;

#define PH8(afbase, SWZ, BFARR, STMT, WAIT)                                         \
  {                                                                                 \
    bf16x8 af[4];                                                                   \
    _Pragma("unroll") for (int mf = 0; mf < 4; ++mf)                                \
      af[mf] = *(const bf16x8*)(Ah + ((afbase) + mf) * 1024 + lr * 64 + (SWZ));     \
    STMT;                                                                           \
    WAIT;                                                                           \
    __builtin_amdgcn_s_barrier();                                                   \
    asm volatile("" ::: "memory");                                                  \
    __builtin_amdgcn_s_setprio(1);                                                  \
    _Pragma("unroll") for (int mf = 0; mf < 4; ++mf)                                \
    _Pragma("unroll") for (int nf = 0; nf < 4; ++nf)                                \
      acc[(afbase) + mf][nf] =                                                      \
          __builtin_amdgcn_mfma_f32_16x16x32_bf16(af[mf], BFARR[nf], acc[(afbase) + mf][nf], 0, 0, 0); \
    __builtin_amdgcn_s_setprio(0);                                                  \
    __builtin_amdgcn_s_barrier();                                                   \
    asm volatile("" ::: "memory");                                                  \
  }

  for (int t = 0; t < nk; ++t) {
    const int b = t & 1;
    const uint16_t* Ah = lds8[b * 4 + wr];
    const uint16_t* Bh = lds8[b * 4 + 2 + (wc >> 1)];
    const int brow = ((wc & 1) * 64 + lr) * 64;

    bf16x8 bf0[4], bf1[4];
#pragma unroll
    for (int nf = 0; nf < 4; ++nf) {
      bf0[nf] = *(const bf16x8*)(Bh + brow + nf * 1024 + aswz0);
      bf1[nf] = *(const bf16x8*)(Bh + brow + nf * 1024 + aswz1);
    }

    PH8(0, aswz0, bf0, if (t + 1 < nk) ST8(0, b ^ 1, 0, t + 1), )
    PH8(4, aswz0, bf0, if (t + 1 < nk) ST8(0, b ^ 1, 1, t + 1), )
    PH8(0, aswz1, bf1, if (t + 2 < nk) ST8(1, b, 0, t + 2), )
    PH8(4, aswz1, bf1, if (t + 2 < nk) ST8(1, b, 1, t + 2),
        if (t + 2 < nk) { asm volatile("s_waitcnt vmcnt(4)" ::: "memory"); }
        else { asm volatile("s_waitcnt vmcnt(0)" ::: "memory"); })
  }
#undef PH8
#undef ST8

  // ---- epilogue: rope (q/k) via packed float2 cs table, or LDS-transpose (v) ----
  if (n0 < 2560) {
    const bool isq = (n0 < E_DIM);
    const bool odd = lr & 1;
#pragma unroll
    for (int mf = 0; mf < 8; ++mf)
#pragma unroll
      for (int nf = 0; nf < 4; ++nf) {
        const int ncol = n0 + wc * 64 + nf * 16 + lr;
        const int d = ncol & 127;
        const int dd = d >> 1;
        uint16_t* dstb = isq ? (q_r + (size_t)(ncol >> 7) * S_LEN * D_DIM)
                             : (k_r + (size_t)((ncol >> 7) - 16) * S_LEN * D_DIM);
#pragma unroll
        for (int r = 0; r < 4; ++r) {
          const int s = m0 + wr * 128 + mf * 16 + lq * 4 + r;
          const float v = acc[mf][nf][r];
          const float p = __shfl_xor(v, 1);
          const float2 cs = csb[s * 64 + dd];
          float o = odd ? (p * cs.y + v * cs.x) : (v * cs.x - p * cs.y);
          if (isq) o *= SCALE;
          dstb[(size_t)s * D_DIM + d] = f2bf(o);
        }
      }
  } else {
    uint16_t* vT = lds8[w];  // [64 d][128 s], swizzled
#pragma unroll
    for (int mf = 0; mf < 8; ++mf)
#pragma unroll
      for (int nf = 0; nf < 4; ++nf) {
        const int dl = nf * 16 + lr;
        const int s0 = mf * 16 + lq * 4;
        u16x4 pv;
        pv[0] = f2bf(acc[mf][nf][0]); pv[1] = f2bf(acc[mf][nf][1]);
        pv[2] = f2bf(acc[mf][nf][2]); pv[3] = f2bf(acc[mf][nf][3]);
        *(u16x4*)(vT + dl * 128 + (s0 ^ ((dl & 15) << 3))) = pv;
      }
    const int vg = ((n0 - 2560) + wc * 64) >> 7;
    uint16_t* dstv = v_t + ((size_t)vg * D_DIM + (wc & 1) * 64) * S_LEN;
#pragma unroll
    for (int it = 0; it < 16; ++it) {
      const int dl = it * 4 + lq;
      const int sc = lr * 8;
      u16x8 vv = *(const u16x8*)(vT + dl * 128 + (sc ^ ((dl & 15) << 3)));
      *(u16x8*)(dstv + (size_t)dl * S_LEN + m0 + wr * 128 + sc) = vv;
    }
  }
}

// ---------------- flash attention, window [p-1024, p] ----------------
// Flattened 512-block grid with head-major-per-XCD mapping: XCD x gets heads
// {2x,2x+1}, so each XCD's 4MB L2 holds exactly one KV-group's K+V (4MB).
__global__ __launch_bounds__(256, 2) void attn_kernel(
    const uint16_t* __restrict__ q_r, const uint16_t* __restrict__ k_r,
    const uint16_t* __restrict__ v_t, uint16_t* __restrict__ o_r)
{
  __shared__ __align__(16) uint16_t sK[2][64 * 128];   // [key][d], swizzled
  __shared__ __align__(16) uint16_t sVT[2][128 * 64];  // [d][key], swizzled
  const int bid = blockIdx.x;
  const int work = (bid & 7) * 64 + (bid >> 3);  // XCD-major remap
  const int h = work >> 5, g = h >> 2;
  const int q0 = (work & 31) * 128;
  const int tid = threadIdx.x, w = tid >> 6, lane = tid & 63;
  const int lc = lane & 31, hi = lane >> 5;
  const int pmin = q0 + w * 32, pmax = pmin + 31;
  const int pq = pmin + lc;

  bf16x8 aq[8];
  {
    const uint16_t* qb = q_r + ((size_t)h * S_LEN + pq) * D_DIM + hi * 8;
#pragma unroll
    for (int ks = 0; ks < 8; ++ks) aq[ks] = *(const bf16x8*)(qb + ks * 16);
  }
  f32x16 accO[4];
#pragma unroll
  for (int dt = 0; dt < 4; ++dt) accO[dt] = 0;
  float M = -1e30f, L = 0.f;

  const int jstart = (q0 >= 1024) ? (q0 - 1024) : 0;
  const int nt = (q0 + 128 - jstart) >> 6;
  const char* kb = (const char*)(k_r + ((size_t)g * S_LEN + jstart) * D_DIM);
  const char* vb = (const char*)(v_t + (size_t)g * D_DIM * S_LEN + jstart);

  const int kc_row = lane >> 4;
  const int k_col0 = (lane & 15) << 4;
  const int v_scol = (((lane & 7) ^ (lane >> 3)) << 4);
  const int v_row = lane >> 3;

#define STAGE_KV(buf, tt)                                                              \
  {                                                                                    \
    const char* kt_ = kb + (size_t)(tt) * 16384;                                       \
    const char* vt_ = vb + (size_t)(tt) * 128;                                         \
    _Pragma("unroll")                                                                  \
    for (int it = 0; it < 4; ++it) {                                                   \
      const int c = w * 4 + it;                                                        \
      const int krow = c * 4 + kc_row;                                                 \
      const int kscol = k_col0 ^ ((krow & 7) << 4);                                    \
      gload_lds16(kt_ + krow * 256 + kscol, (char*)sK[buf] + c * 1024 + lane * 16);    \
      const int vrow = c * 8 + v_row;                                                  \
      gload_lds16(vt_ + (size_t)vrow * (S_LEN * 2) + v_scol,                           \
                  (char*)sVT[buf] + c * 1024 + lane * 16);                             \
    }                                                                                  \
  }

  STAGE_KV(0, 0)
  asm volatile("s_waitcnt vmcnt(0)" ::: "memory");
  __syncthreads();

  for (int t = 0; t < nt; ++t) {
    const int b = t & 1;
    if (t + 1 < nt) STAGE_KV(b ^ 1, t + 1)
    const int j0 = jstart + t * 64;
    const uint16_t* Kb = sK[b];
    const uint16_t* Vb = sVT[b];

    const bool active = (j0 <= pmax) && (j0 + 63 + 1024 >= pmin);
    if (active) {
      f32x16 accS[2];
      accS[0] = 0; accS[1] = 0;
      __builtin_amdgcn_s_setprio(1);
#pragma unroll
      for (int rt = 0; rt < 2; ++rt) {
        const int krow = rt * 32 + lc;
        const int ksw = (krow & 7) << 3;
#pragma unroll
        for (int ks = 0; ks < 8; ++ks) {
          bf16x8 ak = *(const bf16x8*)(Kb + krow * 128 + ((ks * 16 + hi * 8) ^ ksw));
          accS[rt] = __builtin_amdgcn_mfma_f32_32x32x16_bf16(ak, aq[ks], accS[rt], 0, 0, 0);
        }
      }
      __builtin_amdgcn_s_setprio(0);

      const bool need_mask = (j0 + 63 > pmin) || (j0 < pmax - 1024);
      if (need_mask) {
#pragma unroll
        for (int rt = 0; rt < 2; ++rt)
#pragma unroll
          for (int c = 0; c < 16; ++c) {
            const int j = j0 + rt * 32 + (c & 3) + 8 * (c >> 2) + 4 * hi;
            const bool ok = (j <= pq) && (j + 1024 >= pq);
            accS[rt][c] = ok ? accS[rt][c] : -1e30f;
          }
      }

      float mx = accS[0][0];
#pragma unroll
      for (int rt = 0; rt < 2; ++rt)
#pragma unroll
        for (int c = 0; c < 16; ++c) mx = fmaxf(mx, accS[rt][c]);
      mx = fmaxf(mx, __shfl_xor(mx, 32));

      if (__any(mx > M + 4.f)) {
        const float Mn = fmaxf(M, mx);
        const float al = __expf(M - Mn);
        M = Mn;
        L *= al;
        float alr[16];
#pragma unroll
        for (int c = 0; c < 16; ++c) alr[c] = __shfl(al, (c & 3) + 8 * (c >> 2) + 4 * hi);
#pragma unroll
        for (int dt = 0; dt < 4; ++dt)
#pragma unroll
          for (int c = 0; c < 16; ++c) accO[dt][c] *= alr[c];
      }

      float rs = 0.f;
#pragma unroll
      for (int rt = 0; rt < 2; ++rt)
#pragma unroll
        for (int c = 0; c < 16; ++c) {
          const float pv = __expf(accS[rt][c] - M);
          accS[rt][c] = pv;
          rs += pv;
        }
      rs += __shfl_xor(rs, 32);
      L += rs;

      __builtin_amdgcn_s_setprio(1);
#pragma unroll
      for (int rt = 0; rt < 2; ++rt) {
        uint32_t wv[8];
#pragma unroll
        for (int jj = 0; jj < 8; ++jj)
          wv[jj] = packbf(accS[rt][2 * jj], accS[rt][2 * jj + 1]);
        plswap(wv[0], wv[2]); plswap(wv[1], wv[3]);
        plswap(wv[4], wv[6]); plswap(wv[5], wv[7]);
#pragma unroll
        for (int sub = 0; sub < 2; ++sub) {
          union { uint32_t u[4]; bf16x8 v; } ap;
          ap.u[0] = wv[sub * 4 + 0]; ap.u[1] = wv[sub * 4 + 1];
          ap.u[2] = wv[sub * 4 + 2]; ap.u[3] = wv[sub * 4 + 3];
          const int kbase = rt * 32 + sub * 16 + hi * 8;
#pragma unroll
          for (int dt = 0; dt < 4; ++dt) {
            const int vrow = dt * 32 + lc;
            bf16x8 bv = *(const bf16x8*)(Vb + vrow * 64 + (kbase ^ ((vrow & 7) << 3)));
            accO[dt] = __builtin_amdgcn_mfma_f32_32x32x16_bf16(ap.v, bv, accO[dt], 0, 0, 0);
          }
        }
      }
      __builtin_amdgcn_s_setprio(0);
    }

    asm volatile("s_waitcnt vmcnt(0)" ::: "memory");
    __syncthreads();
  }

  const float ivl = 1.f / L;
  float il[16];
#pragma unroll
  for (int c = 0; c < 16; ++c) il[c] = __shfl(ivl, (c & 3) + 8 * (c >> 2) + 4 * hi);
#pragma unroll
  for (int dt = 0; dt < 4; ++dt)
#pragma unroll
    for (int c = 0; c < 16; ++c) {
      const int p = pmin + (c & 3) + 8 * (c >> 2) + 4 * hi;
      o_r[(size_t)p * E_DIM + h * D_DIM + dt * 32 + lc] = f2bf(accO[dt][c] * il[c]);
    }
}

extern "C" void kernel_launch(void* const* d_in, const int* in_sizes, int n_in,
                              void* d_out, int out_size, void* d_ws, size_t ws_size,
                              hipStream_t stream) {
  const float* x     = (const float*)d_in[0];
  const float* fcos  = (const float*)d_in[1];
  const float* fsin  = (const float*)d_in[2];
  const float* w_in  = (const float*)d_in[3];
  const float* w_out = (const float*)d_in[4];
  float* out = (float*)d_out;

  char* ws = (char*)d_ws;
  size_t off = 0;
  uint16_t* w_inT  = (uint16_t*)(ws + off); off += (size_t)QKV_N * E_DIM * 2;
  uint16_t* w_outT = (uint16_t*)(ws + off); off += (size_t)E_DIM * E_DIM * 2;
  uint16_t* q_r    = (uint16_t*)(ws + off); off += (size_t)H_NUM * S_LEN * D_DIM * 2;
  uint16_t* k_r    = (uint16_t*)(ws + off); off += (size_t)G_NUM * S_LEN * D_DIM * 2;
  uint16_t* v_t    = (uint16_t*)(ws + off); off += (size_t)G_NUM * D_DIM * S_LEN * 2;
  uint16_t* o_r    = (uint16_t*)(ws + off); off += (size_t)S_LEN * E_DIM * 2;
  float2*   csb    = (float2*)(ws + off);   off += (size_t)S_LEN * 64 * 8;
  // x_bf aliases o_r: consumed by gemm8_qkv before attn writes o_r (stream-ordered).
  uint16_t* x_bf   = o_r;

  // fused prep (conv + both weight transposes + cs table)
  prep_all<<<4096 + 1536 + 1024 + 1024, 256, 0, stream>>>(
      x, w_in, w_out, fcos, fsin, x_bf, w_inT, w_outT, csb);
  // 8-phase 256x256 qkv GEMM + rope + split (192 blocks, %8==0)
  gemm8_qkv<<<(S_LEN / 256) * (QKV_N / 256), 512, 0, stream>>>(
      x_bf, w_inT, csb, q_r, k_r, v_t, E_DIM, S_LEN / 256);
  // attention (flattened 512 blocks, head-major per XCD)
  attn_kernel<<<512, 256, 0, stream>>>(q_r, k_r, v_t, o_r);
  // out = o @ w_out  (fp32 out)
  gemm_bt<<<(S_LEN / 128) * (E_DIM / 128), 256, 0, stream>>>(o_r, w_outT, nullptr, out,
                                                             S_LEN, E_DIM, E_DIM, S_LEN / 128);
}